// Round 4
// baseline (295.587 us; speedup 1.0000x reference)
//
#include <hip/hip_runtime.h>
#include <stdint.h>
#include <math.h>

typedef unsigned short u16;
typedef __bf16 bf16x8 __attribute__((ext_vector_type(8)));
typedef float f32x4 __attribute__((ext_vector_type(4)));

#define NEG_ -10000.0f

__device__ __forceinline__ u16 f2bf(float f){
  unsigned u = __float_as_uint(f);
  unsigned r = (u + 0x7fffu + ((u >> 16) & 1u)) >> 16;
  return (u16)r;
}

__device__ __forceinline__ float gelu_exact(float v){
  return 0.5f * v * (1.f + erff(v * 0.70710678118654752f));
}
__device__ __forceinline__ float sigmoidf_(float z){ return 1.f / (1.f + expf(-z)); }

__device__ __forceinline__ void async_load16(const void* g, void* lds){
  typedef const __attribute__((address_space(1))) unsigned int* gp_t;
  typedef __attribute__((address_space(3))) unsigned int* lp_t;
  __builtin_amdgcn_global_load_lds((gp_t)(uintptr_t)g, (lp_t)(uintptr_t)lds, 16, 0, 0);
}

__device__ __forceinline__ unsigned swz(unsigned o){ return o ^ ((o >> 3) & 0x70u); }

// ---------------- gates + padded bias ----------------
__global__ __launch_bounds__(256) void prep_gates(
    const float* __restrict__ s, const int* __restrict__ t,
    const float* __restrict__ efc1, const float* __restrict__ efc2,
    const float* __restrict__ elarger, const float* __restrict__ fc1_b,
    float* __restrict__ gfc1p, float* __restrict__ b1p,
    float* __restrict__ gfc2, float* __restrict__ glarger)
{
  int i = blockIdx.x * 256 + threadIdx.x;
  float sv = s[0]; int tt = t[0];
  if (i < 2048){
    float g = 0.f, b = 0.f;
    if (i < 2000){ g = sigmoidf_(sv * efc1[tt * 2000 + i]); b = fc1_b[i]; }
    gfc1p[i] = g; b1p[i] = b;
  }
  if (i < 768){
    gfc2[i]    = sigmoidf_(sv * efc2[tt * 768 + i]);
    glarger[i] = sigmoidf_(sv * elarger[tt * 768 + i]);
  }
}

// ---------------- weight conversions (zero-padded, vectorized) ----------------
__global__ __launch_bounds__(256) void conv_w1(const float* __restrict__ fc1_w, u16* __restrict__ Bw1){
  int q = blockIdx.x * 256 + threadIdx.x;              // 4 elems each, [2048][768]
  if (q >= 2048 * 192) return;
  int idx = q * 4;
  int n = idx / 768, k = idx % 768;
  ushort4 o;
  if (n < 2000){
    float4 v = *(const float4*)(fc1_w + (size_t)n * 768 + k);
    o.x = f2bf(v.x); o.y = f2bf(v.y); o.z = f2bf(v.z); o.w = f2bf(v.w);
  } else { o.x = o.y = o.z = o.w = 0; }
  *(ushort4*)(Bw1 + idx) = o;
}
__global__ __launch_bounds__(256) void conv_w2(const float* __restrict__ fc2_w, u16* __restrict__ Bw2){
  int q = blockIdx.x * 256 + threadIdx.x;              // 4 elems each, [768][2048]
  if (q >= 768 * 512) return;
  int idx = q * 4;
  int h = idx / 2048, k = idx % 2048;
  ushort4 o;
  if (k < 2000){                                        // 2000%4==0 -> whole float4 valid
    float4 v = *(const float4*)(fc2_w + (size_t)h * 2000 + k);
    o.x = f2bf(v.x); o.y = f2bf(v.y); o.z = f2bf(v.z); o.w = f2bf(v.w);
  } else { o.x = o.y = o.z = o.w = 0; }
  *(ushort4*)(Bw2 + idx) = o;
}

// ---------------- sem capsules + squash + priors + dynamic routing (wave-parallel) ----
__global__ __launch_bounds__(256) void sem_route(
    const float* __restrict__ x, const int* __restrict__ t_ptr,
    const float* __restrict__ sem_w, const float* __restrict__ sem_b,
    const float* __restrict__ rw, float* __restrict__ voteflat)
{
  __shared__ float semv[4][4][32];
  const int tid  = threadIdx.x;
  const int wid  = tid >> 6, lane = tid & 63;
  const int tok0 = (blockIdx.x * 4 + wid) * 4;

  float4 xr[4][3];
#pragma unroll
  for (int tk = 0; tk < 4; tk++)
#pragma unroll
    for (int j = 0; j < 3; j++)
      xr[tk][j] = *(const float4*)(x + (size_t)(tok0 + tk) * 768 + j * 256 + lane * 4);

  for (int cap = 0; cap < 30; ++cap){
    const int c = cap / 10, tt2 = cap % 10;
    const float* wrow = sem_w + (size_t)(tt2 * 3 + c) * 768;
    const float4 w0 = *(const float4*)(wrow +       lane * 4);
    const float4 w1 = *(const float4*)(wrow + 256 + lane * 4);
    const float4 w2 = *(const float4*)(wrow + 512 + lane * 4);
    float d[4];
#pragma unroll
    for (int tk = 0; tk < 4; tk++){
      const float4 a0 = xr[tk][0], a1 = xr[tk][1], a2 = xr[tk][2];
      d[tk] = a0.x * w0.x + a0.y * w0.y + a0.z * w0.z + a0.w * w0.w
            + a1.x * w1.x + a1.y * w1.y + a1.z * w1.z + a1.w * w1.w
            + a2.x * w2.x + a2.y * w2.y + a2.z * w2.z + a2.w * w2.w;
    }
#pragma unroll
    for (int m = 1; m < 64; m <<= 1){
#pragma unroll
      for (int tk = 0; tk < 4; tk++) d[tk] += __shfl_xor(d[tk], m, 64);
    }
    if (lane < 4) semv[wid][lane][cap] = d[lane] + sem_b[tt2 * 3 + c];
  }
  __syncthreads();

  if (lane < 12){
    const int tk = lane / 3, c = lane % 3;
    float v[10]; float sq = 0.f;
#pragma unroll
    for (int j = 0; j < 10; j++){ v[j] = semv[wid][tk][c * 10 + j]; sq += v[j] * v[j]; }
    sq += 1e-16f;
    const float scale = (sq / (1.f + sq)) / sqrtf(sq);
#pragma unroll
    for (int j = 0; j < 10; j++) semv[wid][tk][c * 10 + j] = v[j] * scale;
  }
  __syncthreads();

  if (lane < 12){
    const int tk = lane / 3, m = lane % 3;
    const int tt = t_ptr[0];
    float p[10][3];
#pragma unroll
    for (int r = 0; r < 10; r++){
      const float x0 = semv[wid][tk][r * 3 + 0];
      const float x1 = semv[wid][tk][r * 3 + 1];
      const float x2 = semv[wid][tk][r * 3 + 2];
      const float* rwp = rw + m * 90 + r * 9;
#pragma unroll
      for (int d = 0; d < 3; d++)
        p[r][d] = x0 * rwp[d] + x1 * rwp[3 + d] + x2 * rwp[6 + d];
    }
    float lg[10];
#pragma unroll
    for (int r = 0; r < 10; r++) lg[r] = 0.f;
    float v0 = 0.f, v1 = 0.f, v2 = 0.f;
    for (int it = 0; it < 3; ++it){
      float lr[10]; float mx = -3.0e38f;
#pragma unroll
      for (int r = 0; r < 10; r++){ lr[r] = (r <= tt) ? lg[r] : NEG_; mx = fmaxf(mx, lr[r]); }
      float e[10]; float sum = 0.f;
#pragma unroll
      for (int r = 0; r < 10; r++){ e[r] = expf(lr[r] - mx); sum += e[r]; }
      const float inv = 1.f / sum;
      v0 = 0.f; v1 = 0.f; v2 = 0.f;
#pragma unroll
      for (int r = 0; r < 10; r++){
        const float pr = e[r] * inv;
        v0 += pr * p[r][0]; v1 += pr * p[r][1]; v2 += pr * p[r][2];
      }
      if (it < 2){
        float sq = v0 * v0 + v1 * v1 + v2 * v2 + 1e-16f;
        float scale = (sq / (1.f + sq)) / sqrtf(sq);
        const float o0 = v0 * scale, o1 = v1 * scale, o2 = v2 * scale;
#pragma unroll
        for (int r = 0; r < 10; r++) lg[r] += p[r][0] * o0 + p[r][1] * o1 + p[r][2] * o2;
      }
    }
    float* dst = voteflat + (size_t)m * 49152 + (size_t)(tok0 + tk) * 3;
    dst[0] = v0; dst[1] = v1; dst[2] = v2;
  }
}

// ---------------- h_pre = x + (h_caps @ larger_w^T + b) * glarger  -> bf16 (vec4) -------
__global__ __launch_bounds__(256) void hpre_kernel(
    const float* __restrict__ x, const float* __restrict__ voteflat,
    const float* __restrict__ larger_w, const float* __restrict__ larger_b,
    const float* __restrict__ glarger, u16* __restrict__ hpre)
{
  size_t q = (size_t)blockIdx.x * 256 + threadIdx.x;   // 4 h-elems per thread
  if (q >= (size_t)16384 * 192) return;
  size_t n = q / 192;
  int h0 = (int)(q % 192) * 4;
  float vt[9];
#pragma unroll
  for (int m = 0; m < 3; m++)
#pragma unroll
    for (int c = 0; c < 3; c++)
      vt[m * 3 + c] = voteflat[(size_t)m * 49152 + n * 3 + c];
  float4 xv = *(const float4*)(x + n * 768 + h0);
  ushort4 ov;
  float xa[4] = {xv.x, xv.y, xv.z, xv.w};
  u16 oa[4];
#pragma unroll
  for (int j = 0; j < 4; j++){
    const int h = h0 + j;
    const float* lw = larger_w + (size_t)h * 9;
    float acc = larger_b[h];
#pragma unroll
    for (int k = 0; k < 9; k++) acc += vt[k] * lw[k];
    oa[j] = f2bf(xa[j] + acc * glarger[h]);
  }
  ov.x = oa[0]; ov.y = oa[1]; ov.z = oa[2]; ov.w = oa[3];
  *(ushort4*)(hpre + n * 768 + h0) = ov;
}

// ---------------- 256x256 bf16 MFMA GEMM, C = A(MxK) * B(NxK)^T -------------------------
// T1 XCD swizzle + T2 LDS XOR swizzle + counted-vmcnt double-buffer + T5 setprio.
// 2 barriers per K-tile; LDS reads software-pipelined in registers so the LDS pipe
// overlaps the matrix pipe within and across waves.
// MODE 0: store bf16(gelu(acc+bias)*gate);  MODE 1: store f32 xres + gelu(acc+bias)*gate.
#define MM4(af, base) do { \
  __builtin_amdgcn_s_setprio(1); \
  _Pragma("unroll") \
  for (int fi = 0; fi < 2; ++fi) \
    _Pragma("unroll") \
    for (int g = 0; g < 4; ++g) \
      _Pragma("unroll") \
      for (int ks = 0; ks < 2; ++ks) \
        acc[(base) + fi][g] = __builtin_amdgcn_mfma_f32_16x16x32_bf16( \
            af[fi][ks], bfr[g][ks], acc[(base) + fi][g], 0, 0, 0); \
  __builtin_amdgcn_s_setprio(0); \
} while (0)

#define LDA(dst, qq) do { \
  _Pragma("unroll") \
  for (int fi = 0; fi < 2; ++fi) \
    _Pragma("unroll") \
    for (int ks = 0; ks < 2; ++ks){ \
      unsigned o = (unsigned)(((((qq) * 2 + fi) * 16 + (l & 15)) << 7) + ks * 64 + ((l >> 4) << 4)); \
      dst[fi][ks] = *(const bf16x8*)(abase + swz(o)); \
    } \
} while (0)

template<int MODE, int NDIM, int KDIM>
__global__ __launch_bounds__(512, 2) void gemm8(
    const u16* __restrict__ A, const u16* __restrict__ B,
    const float* __restrict__ bias, const float* __restrict__ gate,
    const float* __restrict__ xres, void* __restrict__ Cout, int NT_N)
{
  __shared__ __align__(16) u16 As[2][16384];
  __shared__ __align__(16) u16 Bs[2][16384];
  constexpr int NT = KDIM / 64;
  constexpr int NITER = NT / 2;

  const int nwg = (int)gridDim.x;              // multiple of 8
  const int cpx = nwg >> 3;
  const int wg  = ((int)blockIdx.x & 7) * cpx + ((int)blockIdx.x >> 3);
  const int bm = wg / NT_N, bn = wg % NT_N;
  const int m0 = bm * 256, n0 = bn * 256;
  const int tid = (int)threadIdx.x;
  const int w = tid >> 6, l = tid & 63;
  const int wr = w >> 2, wc = w & 3;           // 2 x 4 wave grid; wave tile 128 x 64

  f32x4 acc[8][4];
#pragma unroll
  for (int i = 0; i < 8; i++)
#pragma unroll
    for (int j = 0; j < 4; j++)
      acc[i][j] = (f32x4){0.f, 0.f, 0.f, 0.f};

  auto stage = [&](const u16* __restrict__ src, int r0, int k0, u16* lds){
#pragma unroll
    for (int j = 0; j < 4; ++j){
      const int half = j >> 1, jj = j & 1;
      unsigned o  = (unsigned)(jj * 8192 + tid * 16);
      unsigned lo = swz(o);
      int row  = half * 128 + (int)(lo >> 7);
      int colb = (int)(lo & 127u);
      const u16* g = src + (size_t)(r0 + row) * KDIM + (k0 + (colb >> 1));
      char* d = (char*)lds + half * 16384 + jj * 8192 + w * 1024;
      async_load16(g, d);
    }
  };

  auto compute_tile = [&](int cur){
    const char* abase = (const char*)As[cur] + wr * 16384;
    const char* bbase = (const char*)Bs[cur] + (wc >> 1) * 16384;
    bf16x8 bfr[4][2];
#pragma unroll
    for (int g = 0; g < 4; ++g)
#pragma unroll
      for (int ks = 0; ks < 2; ++ks){
        unsigned o = (unsigned)((((wc & 1) * 64 + g * 16 + (l & 15)) << 7) + ks * 64 + ((l >> 4) << 4));
        bfr[g][ks] = *(const bf16x8*)(bbase + swz(o));
      }
    bf16x8 afA[2][2], afB[2][2];
    LDA(afA, 0);
    LDA(afB, 1);
    MM4(afA, 0);          // phase 0 MFMAs while phase-1 reads are in the LDS pipe
    LDA(afA, 2);
    MM4(afB, 2);
    LDA(afB, 3);
    MM4(afA, 4);
    MM4(afB, 6);
  };

  // prologue: tile0 -> buf0, tile1 -> buf1; wait tile0 (8 loads of tile1 in flight)
  stage(A, m0, 0, As[0]);  stage(B, n0, 0, Bs[0]);
  stage(A, m0, 64, As[1]); stage(B, n0, 64, Bs[1]);
  asm volatile("s_waitcnt vmcnt(8)" ::: "memory");
  __builtin_amdgcn_s_barrier();

  for (int i = 0; i < NITER - 1; ++i){
    compute_tile(0);                                   // tile 2i (buf0)
    asm volatile("s_waitcnt lgkmcnt(0)" ::: "memory"); // my buf0 reads complete
    __builtin_amdgcn_s_barrier();                      // all waves done with buf0
    stage(A, m0, (2 * i + 2) * 64, As[0]);             // tile 2i+2 -> buf0
    stage(B, n0, (2 * i + 2) * 64, Bs[0]);
    asm volatile("s_waitcnt vmcnt(8)" ::: "memory");   // tile 2i+1 landed; 2i+2 in flight
    __builtin_amdgcn_s_barrier();
    compute_tile(1);                                   // tile 2i+1 (buf1)
    asm volatile("s_waitcnt lgkmcnt(0)" ::: "memory");
    __builtin_amdgcn_s_barrier();
    stage(A, m0, (2 * i + 3) * 64, As[1]);             // tile 2i+3 -> buf1
    stage(B, n0, (2 * i + 3) * 64, Bs[1]);
    asm volatile("s_waitcnt vmcnt(8)" ::: "memory");   // tile 2i+2 landed; 2i+3 in flight
    __builtin_amdgcn_s_barrier();
  }
  compute_tile(0);                                     // tile NT-2
  asm volatile("s_waitcnt vmcnt(0)" ::: "memory");     // drain tile NT-1
  __builtin_amdgcn_s_barrier();
  compute_tile(1);                                     // tile NT-1

  // epilogue
#pragma unroll
  for (int f = 0; f < 8; ++f){
    const int rowb = m0 + wr * 128 + f * 16 + ((l >> 4) << 2);
#pragma unroll
    for (int g = 0; g < 4; ++g){
      const int col = n0 + wc * 64 + g * 16 + (l & 15);
      const float bv = bias[col], gv = gate[col];
#pragma unroll
      for (int j = 0; j < 4; ++j){
        const int row = rowb + j;
        float v = acc[f][g][j] + bv;
        float gl = gelu_exact(v) * gv;
        if (MODE == 0){
          ((u16*)Cout)[(size_t)row * NDIM + col] = f2bf(gl);
        } else {
          size_t off = (size_t)row * NDIM + col;
          ((float*)Cout)[off] = xres[off] + gl;
        }
      }
    }
  }
}

// ---------------- launcher ----------------
extern "C" void kernel_launch(void* const* d_in, const int* in_sizes, int n_in,
                              void* d_out, int out_size, void* d_ws, size_t ws_size,
                              hipStream_t stream)
{
  const float* x       = (const float*)d_in[0];
  const int*   t       = (const int*)  d_in[1];
  const float* s       = (const float*)d_in[2];
  const float* fc1_w   = (const float*)d_in[3];
  const float* fc1_b   = (const float*)d_in[4];
  const float* fc2_w   = (const float*)d_in[5];
  const float* fc2_b   = (const float*)d_in[6];
  const float* efc1    = (const float*)d_in[7];
  const float* efc2    = (const float*)d_in[8];
  const float* sem_w   = (const float*)d_in[9];
  const float* sem_b   = (const float*)d_in[10];
  const float* rw      = (const float*)d_in[11];
  const float* larger_w= (const float*)d_in[12];
  const float* larger_b= (const float*)d_in[13];
  const float* elarger = (const float*)d_in[14];

  char* ws = (char*)d_ws;
  float* vote    = (float*)(ws + 0);         //  589824 B  [3][16384][3] f32
  float* gfc1p   = (float*)(ws + 589824);    //    8192 B  [2048]
  float* b1p     = (float*)(ws + 598016);    //    8192 B  [2048]
  float* gfc2    = (float*)(ws + 606208);    //    3072 B  [768]
  float* glarger = (float*)(ws + 609280);    //    3072 B  [768]
  u16*   Bw1     = (u16*)  (ws + 612352);    // 3145728 B  [2048][768] bf16
  u16*   Bw2     = (u16*)  (ws + 3758080);   // 3145728 B  [768][2048] bf16
  u16*   hpre    = (u16*)  (ws + 6903808);   // 25165824 B [16384][768] bf16
  u16*   Hm      = (u16*)  (ws + 32069632);  // 67108864 B [16384][2048] bf16
  // total 99,178,496 B

  prep_gates<<<8, 256, 0, stream>>>(s, t, efc1, efc2, elarger, fc1_b, gfc1p, b1p, gfc2, glarger);
  conv_w1<<<1536, 256, 0, stream>>>(fc1_w, Bw1);
  conv_w2<<<1536, 256, 0, stream>>>(fc2_w, Bw2);
  sem_route<<<1024, 256, 0, stream>>>(x, t, sem_w, sem_b, rw, vote);
  hpre_kernel<<<12288, 256, 0, stream>>>(x, vote, larger_w, larger_b, glarger, hpre);
  gemm8<0, 2048, 768><<<512, 512, 0, stream>>>(hpre, Bw1, b1p, gfc1p, nullptr, (void*)Hm, 8);
  gemm8<1, 768, 2048><<<192, 512, 0, stream>>>(Hm, Bw2, fc2_b, gfc2, x, d_out, 3);
}

// Round 5
// 293.010 us; speedup vs baseline: 1.0088x; 1.0088x over previous
//
#include <hip/hip_runtime.h>
#include <stdint.h>
#include <math.h>

typedef unsigned short u16;
typedef __bf16 bf16x8 __attribute__((ext_vector_type(8)));
typedef float f32x4 __attribute__((ext_vector_type(4)));

#define NEG_ -10000.0f

__device__ __forceinline__ u16 f2bf(float f){
  unsigned u = __float_as_uint(f);
  unsigned r = (u + 0x7fffu + ((u >> 16) & 1u)) >> 16;
  return (u16)r;
}

__device__ __forceinline__ float gelu_exact(float v){
  return 0.5f * v * (1.f + erff(v * 0.70710678118654752f));
}
__device__ __forceinline__ float sigmoidf_(float z){ return 1.f / (1.f + expf(-z)); }

__device__ __forceinline__ void async_load16(const void* g, void* lds){
  typedef const __attribute__((address_space(1))) unsigned int* gp_t;
  typedef __attribute__((address_space(3))) unsigned int* lp_t;
  __builtin_amdgcn_global_load_lds((gp_t)(uintptr_t)g, (lp_t)(uintptr_t)lds, 16, 0, 0);
}

__device__ __forceinline__ unsigned swz(unsigned o){ return o ^ ((o >> 3) & 0x70u); }

// ---------------- gates + padded bias ----------------
__global__ __launch_bounds__(256) void prep_gates(
    const float* __restrict__ s, const int* __restrict__ t,
    const float* __restrict__ efc1, const float* __restrict__ efc2,
    const float* __restrict__ elarger, const float* __restrict__ fc1_b,
    float* __restrict__ gfc1p, float* __restrict__ b1p,
    float* __restrict__ gfc2, float* __restrict__ glarger)
{
  int i = blockIdx.x * 256 + threadIdx.x;
  float sv = s[0]; int tt = t[0];
  if (i < 2048){
    float g = 0.f, b = 0.f;
    if (i < 2000){ g = sigmoidf_(sv * efc1[tt * 2000 + i]); b = fc1_b[i]; }
    gfc1p[i] = g; b1p[i] = b;
  }
  if (i < 768){
    gfc2[i]    = sigmoidf_(sv * efc2[tt * 768 + i]);
    glarger[i] = sigmoidf_(sv * elarger[tt * 768 + i]);
  }
}

// ---------------- weight conversions (zero-padded, vectorized) ----------------
__global__ __launch_bounds__(256) void conv_w1(const float* __restrict__ fc1_w, u16* __restrict__ Bw1){
  int q = blockIdx.x * 256 + threadIdx.x;              // 4 elems each, [2048][768]
  if (q >= 2048 * 192) return;
  int idx = q * 4;
  int n = idx / 768, k = idx % 768;
  ushort4 o;
  if (n < 2000){
    float4 v = *(const float4*)(fc1_w + (size_t)n * 768 + k);
    o.x = f2bf(v.x); o.y = f2bf(v.y); o.z = f2bf(v.z); o.w = f2bf(v.w);
  } else { o.x = o.y = o.z = o.w = 0; }
  *(ushort4*)(Bw1 + idx) = o;
}
__global__ __launch_bounds__(256) void conv_w2(const float* __restrict__ fc2_w, u16* __restrict__ Bw2){
  int q = blockIdx.x * 256 + threadIdx.x;              // 4 elems each, [768][2048]
  if (q >= 768 * 512) return;
  int idx = q * 4;
  int h = idx / 2048, k = idx % 2048;
  ushort4 o;
  if (k < 2000){                                        // 2000%4==0 -> whole float4 valid
    float4 v = *(const float4*)(fc2_w + (size_t)h * 2000 + k);
    o.x = f2bf(v.x); o.y = f2bf(v.y); o.z = f2bf(v.z); o.w = f2bf(v.w);
  } else { o.x = o.y = o.z = o.w = 0; }
  *(ushort4*)(Bw2 + idx) = o;
}

// ---------------- sem capsules + squash + priors + dynamic routing (wave-parallel) ----
__global__ __launch_bounds__(256) void sem_route(
    const float* __restrict__ x, const int* __restrict__ t_ptr,
    const float* __restrict__ sem_w, const float* __restrict__ sem_b,
    const float* __restrict__ rw, float* __restrict__ voteflat)
{
  __shared__ float semv[4][4][32];
  const int tid  = threadIdx.x;
  const int wid  = tid >> 6, lane = tid & 63;
  const int tok0 = (blockIdx.x * 4 + wid) * 4;

  float4 xr[4][3];
#pragma unroll
  for (int tk = 0; tk < 4; tk++)
#pragma unroll
    for (int j = 0; j < 3; j++)
      xr[tk][j] = *(const float4*)(x + (size_t)(tok0 + tk) * 768 + j * 256 + lane * 4);

  for (int cap = 0; cap < 30; ++cap){
    const int c = cap / 10, tt2 = cap % 10;
    const float* wrow = sem_w + (size_t)(tt2 * 3 + c) * 768;
    const float4 w0 = *(const float4*)(wrow +       lane * 4);
    const float4 w1 = *(const float4*)(wrow + 256 + lane * 4);
    const float4 w2 = *(const float4*)(wrow + 512 + lane * 4);
    float d[4];
#pragma unroll
    for (int tk = 0; tk < 4; tk++){
      const float4 a0 = xr[tk][0], a1 = xr[tk][1], a2 = xr[tk][2];
      d[tk] = a0.x * w0.x + a0.y * w0.y + a0.z * w0.z + a0.w * w0.w
            + a1.x * w1.x + a1.y * w1.y + a1.z * w1.z + a1.w * w1.w
            + a2.x * w2.x + a2.y * w2.y + a2.z * w2.z + a2.w * w2.w;
    }
#pragma unroll
    for (int m = 1; m < 64; m <<= 1){
#pragma unroll
      for (int tk = 0; tk < 4; tk++) d[tk] += __shfl_xor(d[tk], m, 64);
    }
    if (lane < 4) semv[wid][lane][cap] = d[lane] + sem_b[tt2 * 3 + c];
  }
  __syncthreads();

  if (lane < 12){
    const int tk = lane / 3, c = lane % 3;
    float v[10]; float sq = 0.f;
#pragma unroll
    for (int j = 0; j < 10; j++){ v[j] = semv[wid][tk][c * 10 + j]; sq += v[j] * v[j]; }
    sq += 1e-16f;
    const float scale = (sq / (1.f + sq)) / sqrtf(sq);
#pragma unroll
    for (int j = 0; j < 10; j++) semv[wid][tk][c * 10 + j] = v[j] * scale;
  }
  __syncthreads();

  if (lane < 12){
    const int tk = lane / 3, m = lane % 3;
    const int tt = t_ptr[0];
    float p[10][3];
#pragma unroll
    for (int r = 0; r < 10; r++){
      const float x0 = semv[wid][tk][r * 3 + 0];
      const float x1 = semv[wid][tk][r * 3 + 1];
      const float x2 = semv[wid][tk][r * 3 + 2];
      const float* rwp = rw + m * 90 + r * 9;
#pragma unroll
      for (int d = 0; d < 3; d++)
        p[r][d] = x0 * rwp[d] + x1 * rwp[3 + d] + x2 * rwp[6 + d];
    }
    float lg[10];
#pragma unroll
    for (int r = 0; r < 10; r++) lg[r] = 0.f;
    float v0 = 0.f, v1 = 0.f, v2 = 0.f;
    for (int it = 0; it < 3; ++it){
      float lr[10]; float mx = -3.0e38f;
#pragma unroll
      for (int r = 0; r < 10; r++){ lr[r] = (r <= tt) ? lg[r] : NEG_; mx = fmaxf(mx, lr[r]); }
      float e[10]; float sum = 0.f;
#pragma unroll
      for (int r = 0; r < 10; r++){ e[r] = expf(lr[r] - mx); sum += e[r]; }
      const float inv = 1.f / sum;
      v0 = 0.f; v1 = 0.f; v2 = 0.f;
#pragma unroll
      for (int r = 0; r < 10; r++){
        const float pr = e[r] * inv;
        v0 += pr * p[r][0]; v1 += pr * p[r][1]; v2 += pr * p[r][2];
      }
      if (it < 2){
        float sq = v0 * v0 + v1 * v1 + v2 * v2 + 1e-16f;
        float scale = (sq / (1.f + sq)) / sqrtf(sq);
        const float o0 = v0 * scale, o1 = v1 * scale, o2 = v2 * scale;
#pragma unroll
        for (int r = 0; r < 10; r++) lg[r] += p[r][0] * o0 + p[r][1] * o1 + p[r][2] * o2;
      }
    }
    float* dst = voteflat + (size_t)m * 49152 + (size_t)(tok0 + tk) * 3;
    dst[0] = v0; dst[1] = v1; dst[2] = v2;
  }
}

// ---------------- h_pre = x + (h_caps @ larger_w^T + b) * glarger  -> bf16 (vec4) -------
__global__ __launch_bounds__(256) void hpre_kernel(
    const float* __restrict__ x, const float* __restrict__ voteflat,
    const float* __restrict__ larger_w, const float* __restrict__ larger_b,
    const float* __restrict__ glarger, u16* __restrict__ hpre)
{
  size_t q = (size_t)blockIdx.x * 256 + threadIdx.x;   // 4 h-elems per thread
  if (q >= (size_t)16384 * 192) return;
  size_t n = q / 192;
  int h0 = (int)(q % 192) * 4;
  float vt[9];
#pragma unroll
  for (int m = 0; m < 3; m++)
#pragma unroll
    for (int c = 0; c < 3; c++)
      vt[m * 3 + c] = voteflat[(size_t)m * 49152 + n * 3 + c];
  float4 xv = *(const float4*)(x + n * 768 + h0);
  ushort4 ov;
  float xa[4] = {xv.x, xv.y, xv.z, xv.w};
  u16 oa[4];
#pragma unroll
  for (int j = 0; j < 4; j++){
    const int h = h0 + j;
    const float* lw = larger_w + (size_t)h * 9;
    float acc = larger_b[h];
#pragma unroll
    for (int k = 0; k < 9; k++) acc += vt[k] * lw[k];
    oa[j] = f2bf(xa[j] + acc * glarger[h]);
  }
  ov.x = oa[0]; ov.y = oa[1]; ov.z = oa[2]; ov.w = oa[3];
  *(ushort4*)(hpre + n * 768 + h0) = ov;
}

// ---------------- 256x256 8-phase bf16 MFMA GEMM, C = A(MxK) * B(NxK)^T -----------------
// m201-template port: per K-tile j, 4 phases; each phase = {ds_read subtile ||
// stage 1 half-tile -> barrier -> setprio(1) 16 MFMA setprio(0) -> barrier}.
// Stage schedule (race-free by barrier-slip analysis):
//   ph0: A-half0(j+1)  [A of buf (j+1)&1 consumed by end of tile j-1]
//   ph1: A-half1(j+1)
//   ph2: B-half0(j+2)  [B(j) of buf j&1 fully consumed at ph0, one barrier ago]
//   ph3: B-half1(j+2) + counted vmcnt(4) (retires A(j+1),B(j+1); 2 half-tiles in flight)
// MODE 0: store bf16(gelu(acc+bias)*gate);  MODE 1: store f32 xres + gelu(acc+bias)*gate.
template<int MODE, int NDIM, int KDIM>
__global__ __launch_bounds__(512, 2) void gemm8(
    const u16* __restrict__ A, const u16* __restrict__ B,
    const float* __restrict__ bias, const float* __restrict__ gate,
    const float* __restrict__ xres, void* __restrict__ Cout, int NT_N)
{
  __shared__ __align__(16) u16 As[2][16384];   // [buf][half 128 rows x 64 k each]
  __shared__ __align__(16) u16 Bs[2][16384];
  constexpr int NT = KDIM / 64;

  const int nwg = (int)gridDim.x;              // multiple of 8
  const int cpx = nwg >> 3;
  const int wg  = ((int)blockIdx.x & 7) * cpx + ((int)blockIdx.x >> 3);
  const int bm = wg / NT_N, bn = wg % NT_N;
  const int m0 = bm * 256, n0 = bn * 256;
  const int tid = (int)threadIdx.x;
  const int w = tid >> 6, l = tid & 63;
  const int wr = w >> 2, wc = w & 3;           // 2 x 4 wave grid; wave tile 128 x 64

  f32x4 acc[8][4];
#pragma unroll
  for (int i = 0; i < 8; i++)
#pragma unroll
    for (int j = 0; j < 4; j++)
      acc[i][j] = (f32x4){0.f, 0.f, 0.f, 0.f};

  // stage one 128x64 half-tile (16KB): linear LDS dest, swizzled global source
  auto stage_half = [&](const u16* __restrict__ src, int r0, int k0, char* ldsbase){
#pragma unroll
    for (int jj = 0; jj < 2; ++jj){
      unsigned o  = (unsigned)(jj * 8192 + tid * 16);
      unsigned lo = swz(o);
      const u16* g = src + (size_t)(r0 + (int)(lo >> 7)) * KDIM + (k0 + (int)((lo & 127u) >> 1));
      async_load16(g, ldsbase + jj * 8192 + w * 1024);
    }
  };

  // prologue: A(0), B(0), B(1); keep B(1) (4 loads) in flight
  stage_half(A, m0,       0, (char*)As[0]);
  stage_half(A, m0 + 128, 0, (char*)As[0] + 16384);
  stage_half(B, n0,       0, (char*)Bs[0]);
  stage_half(B, n0 + 128, 0, (char*)Bs[0] + 16384);
  stage_half(B, n0,       64, (char*)Bs[1]);
  stage_half(B, n0 + 128, 64, (char*)Bs[1] + 16384);
  asm volatile("s_waitcnt vmcnt(4)" ::: "memory");
  __builtin_amdgcn_s_barrier();

  for (int j = 0; j < NT; ++j){
    const int buf = j & 1;
    const char* abase = (const char*)As[buf] + wr * 16384;
    const char* bbase = (const char*)Bs[buf] + (wc >> 1) * 16384;
    bf16x8 bfr[4][2];
#pragma unroll
    for (int p = 0; p < 4; ++p){
      // --- ds reads for this phase ---
      if (p == 0){
#pragma unroll
        for (int g = 0; g < 4; ++g)
#pragma unroll
          for (int ks = 0; ks < 2; ++ks){
            unsigned o = (unsigned)((((wc & 1) * 64 + g * 16 + (l & 15)) << 7) + ks * 64 + ((l >> 4) << 4));
            bfr[g][ks] = *(const bf16x8*)(bbase + swz(o));
          }
      }
      bf16x8 afr[2][2];
#pragma unroll
      for (int fi = 0; fi < 2; ++fi)
#pragma unroll
        for (int ks = 0; ks < 2; ++ks){
          unsigned o = (unsigned)((((2 * p + fi) * 16 + (l & 15)) << 7) + ks * 64 + ((l >> 4) << 4));
          afr[fi][ks] = *(const bf16x8*)(abase + swz(o));
        }
      // --- stage one half-tile ---
      if (p == 0 && j + 1 < NT) stage_half(A, m0,       (j + 1) * 64, (char*)As[(j + 1) & 1]);
      if (p == 1 && j + 1 < NT) stage_half(A, m0 + 128, (j + 1) * 64, (char*)As[(j + 1) & 1] + 16384);
      if (p == 2 && j + 2 < NT) stage_half(B, n0,       (j + 2) * 64, (char*)Bs[buf]);
      if (p == 3 && j + 2 < NT) stage_half(B, n0 + 128, (j + 2) * 64, (char*)Bs[buf] + 16384);
      if (p == 3){
        if (j < NT - 2)       asm volatile("s_waitcnt vmcnt(4)" ::: "memory");
        else if (j == NT - 2) asm volatile("s_waitcnt vmcnt(0)" ::: "memory");
      }
      asm volatile("" ::: "memory");
      __builtin_amdgcn_s_barrier();
      asm volatile("" ::: "memory");
      // --- 16 MFMA, ks-outer so consecutive MFMAs hit different accumulators ---
      __builtin_amdgcn_s_setprio(1);
#pragma unroll
      for (int ks = 0; ks < 2; ++ks)
#pragma unroll
        for (int fi = 0; fi < 2; ++fi)
#pragma unroll
          for (int g = 0; g < 4; ++g)
            acc[2 * p + fi][g] = __builtin_amdgcn_mfma_f32_16x16x32_bf16(
                afr[fi][ks], bfr[g][ks], acc[2 * p + fi][g], 0, 0, 0);
      __builtin_amdgcn_s_setprio(0);
      asm volatile("" ::: "memory");
      __builtin_amdgcn_s_barrier();
      asm volatile("" ::: "memory");
    }
  }

  // epilogue
#pragma unroll
  for (int f = 0; f < 8; ++f){
    const int rowb = m0 + wr * 128 + f * 16 + ((l >> 4) << 2);
#pragma unroll
    for (int g = 0; g < 4; ++g){
      const int col = n0 + wc * 64 + g * 16 + (l & 15);
      const float bv = bias[col], gv = gate[col];
#pragma unroll
      for (int j = 0; j < 4; ++j){
        const int row = rowb + j;
        float v = acc[f][g][j] + bv;
        float gl = gelu_exact(v) * gv;
        if (MODE == 0){
          ((u16*)Cout)[(size_t)row * NDIM + col] = f2bf(gl);
        } else {
          size_t off = (size_t)row * NDIM + col;
          ((float*)Cout)[off] = xres[off] + gl;
        }
      }
    }
  }
}

// ---------------- launcher ----------------
extern "C" void kernel_launch(void* const* d_in, const int* in_sizes, int n_in,
                              void* d_out, int out_size, void* d_ws, size_t ws_size,
                              hipStream_t stream)
{
  const float* x       = (const float*)d_in[0];
  const int*   t       = (const int*)  d_in[1];
  const float* s       = (const float*)d_in[2];
  const float* fc1_w   = (const float*)d_in[3];
  const float* fc1_b   = (const float*)d_in[4];
  const float* fc2_w   = (const float*)d_in[5];
  const float* fc2_b   = (const float*)d_in[6];
  const float* efc1    = (const float*)d_in[7];
  const float* efc2    = (const float*)d_in[8];
  const float* sem_w   = (const float*)d_in[9];
  const float* sem_b   = (const float*)d_in[10];
  const float* rw      = (const float*)d_in[11];
  const float* larger_w= (const float*)d_in[12];
  const float* larger_b= (const float*)d_in[13];
  const float* elarger = (const float*)d_in[14];

  char* ws = (char*)d_ws;
  float* vote    = (float*)(ws + 0);         //  589824 B  [3][16384][3] f32
  float* gfc1p   = (float*)(ws + 589824);    //    8192 B  [2048]
  float* b1p     = (float*)(ws + 598016);    //    8192 B  [2048]
  float* gfc2    = (float*)(ws + 606208);    //    3072 B  [768]
  float* glarger = (float*)(ws + 609280);    //    3072 B  [768]
  u16*   Bw1     = (u16*)  (ws + 612352);    // 3145728 B  [2048][768] bf16
  u16*   Bw2     = (u16*)  (ws + 3758080);   // 3145728 B  [768][2048] bf16
  u16*   hpre    = (u16*)  (ws + 6903808);   // 25165824 B [16384][768] bf16
  u16*   Hm      = (u16*)  (ws + 32069632);  // 67108864 B [16384][2048] bf16
  // total 99,178,496 B

  prep_gates<<<8, 256, 0, stream>>>(s, t, efc1, efc2, elarger, fc1_b, gfc1p, b1p, gfc2, glarger);
  conv_w1<<<1536, 256, 0, stream>>>(fc1_w, Bw1);
  conv_w2<<<1536, 256, 0, stream>>>(fc2_w, Bw2);
  sem_route<<<1024, 256, 0, stream>>>(x, t, sem_w, sem_b, rw, vote);
  hpre_kernel<<<12288, 256, 0, stream>>>(x, vote, larger_w, larger_b, glarger, hpre);
  gemm8<0, 2048, 768><<<512, 512, 0, stream>>>(hpre, Bw1, b1p, gfc1p, nullptr, (void*)Hm, 8);
  gemm8<1, 768, 2048><<<192, 512, 0, stream>>>(Hm, Bw2, fc2_b, gfc2, x, d_out, 3);
}

// Round 6
// 269.631 us; speedup vs baseline: 1.0963x; 1.0867x over previous
//
#include <hip/hip_runtime.h>
#include <stdint.h>
#include <math.h>

typedef unsigned short u16;
typedef __bf16 bf16x8 __attribute__((ext_vector_type(8)));
typedef float f32x4 __attribute__((ext_vector_type(4)));

#define NEG_ -10000.0f

__device__ __forceinline__ u16 f2bf(float f){
  unsigned u = __float_as_uint(f);
  unsigned r = (u + 0x7fffu + ((u >> 16) & 1u)) >> 16;
  return (u16)r;
}

// gelu exact via Abramowitz-Stegun 7.1.26 erf (|err| < 1.5e-7), ~14 VALU ops
__device__ __forceinline__ float gelu_exact(float v){
  float xe = v * 0.70710678118654752f;
  float ax = fabsf(xe);
  float k  = 1.0f / (1.0f + 0.3275911f * ax);
  float p  = ((((1.061405429f * k - 1.453152027f) * k + 1.421413741f) * k
               - 0.284496736f) * k + 0.254829592f) * k;
  float er = 1.0f - p * __expf(-ax * ax);
  er = copysignf(er, xe);
  return 0.5f * v * (1.0f + er);
}
__device__ __forceinline__ float sigmoidf_(float z){ return 1.f / (1.f + expf(-z)); }

__device__ __forceinline__ void async_load16(const void* g, void* lds){
  typedef const __attribute__((address_space(1))) unsigned int* gp_t;
  typedef __attribute__((address_space(3))) unsigned int* lp_t;
  __builtin_amdgcn_global_load_lds((gp_t)(uintptr_t)g, (lp_t)(uintptr_t)lds, 16, 0, 0);
}

__device__ __forceinline__ unsigned swz(unsigned o){ return o ^ ((o >> 3) & 0x70u); }

// ---------------- gates + padded bias ----------------
__global__ __launch_bounds__(256) void prep_gates(
    const float* __restrict__ s, const int* __restrict__ t,
    const float* __restrict__ efc1, const float* __restrict__ efc2,
    const float* __restrict__ elarger, const float* __restrict__ fc1_b,
    float* __restrict__ gfc1p, float* __restrict__ b1p,
    float* __restrict__ gfc2, float* __restrict__ glarger)
{
  int i = blockIdx.x * 256 + threadIdx.x;
  float sv = s[0]; int tt = t[0];
  if (i < 2048){
    float g = 0.f, b = 0.f;
    if (i < 2000){ g = sigmoidf_(sv * efc1[tt * 2000 + i]); b = fc1_b[i]; }
    gfc1p[i] = g; b1p[i] = b;
  }
  if (i < 768){
    gfc2[i]    = sigmoidf_(sv * efc2[tt * 768 + i]);
    glarger[i] = sigmoidf_(sv * elarger[tt * 768 + i]);
  }
}

// ---------------- weight conversions (zero-padded, vectorized) ----------------
__global__ __launch_bounds__(256) void conv_w1(const float* __restrict__ fc1_w, u16* __restrict__ Bw1){
  int q = blockIdx.x * 256 + threadIdx.x;              // 4 elems each, [2048][768]
  if (q >= 2048 * 192) return;
  int idx = q * 4;
  int n = idx / 768, k = idx % 768;
  ushort4 o;
  if (n < 2000){
    float4 v = *(const float4*)(fc1_w + (size_t)n * 768 + k);
    o.x = f2bf(v.x); o.y = f2bf(v.y); o.z = f2bf(v.z); o.w = f2bf(v.w);
  } else { o.x = o.y = o.z = o.w = 0; }
  *(ushort4*)(Bw1 + idx) = o;
}
__global__ __launch_bounds__(256) void conv_w2(const float* __restrict__ fc2_w, u16* __restrict__ Bw2){
  int q = blockIdx.x * 256 + threadIdx.x;              // 4 elems each, [768][2048]
  if (q >= 768 * 512) return;
  int idx = q * 4;
  int h = idx / 2048, k = idx % 2048;
  ushort4 o;
  if (k < 2000){                                        // 2000%4==0 -> whole float4 valid
    float4 v = *(const float4*)(fc2_w + (size_t)h * 2000 + k);
    o.x = f2bf(v.x); o.y = f2bf(v.y); o.z = f2bf(v.z); o.w = f2bf(v.w);
  } else { o.x = o.y = o.z = o.w = 0; }
  *(ushort4*)(Bw2 + idx) = o;
}

// ---------------- sem capsules + squash + priors + dynamic routing (wave-parallel) ----
__global__ __launch_bounds__(256) void sem_route(
    const float* __restrict__ x, const int* __restrict__ t_ptr,
    const float* __restrict__ sem_w, const float* __restrict__ sem_b,
    const float* __restrict__ rw, float* __restrict__ voteflat)
{
  __shared__ float semv[4][4][32];
  const int tid  = threadIdx.x;
  const int wid  = tid >> 6, lane = tid & 63;
  const int tok0 = (blockIdx.x * 4 + wid) * 4;

  float4 xr[4][3];
#pragma unroll
  for (int tk = 0; tk < 4; tk++)
#pragma unroll
    for (int j = 0; j < 3; j++)
      xr[tk][j] = *(const float4*)(x + (size_t)(tok0 + tk) * 768 + j * 256 + lane * 4);

  for (int cap = 0; cap < 30; ++cap){
    const int c = cap / 10, tt2 = cap % 10;
    const float* wrow = sem_w + (size_t)(tt2 * 3 + c) * 768;
    const float4 w0 = *(const float4*)(wrow +       lane * 4);
    const float4 w1 = *(const float4*)(wrow + 256 + lane * 4);
    const float4 w2 = *(const float4*)(wrow + 512 + lane * 4);
    float d[4];
#pragma unroll
    for (int tk = 0; tk < 4; tk++){
      const float4 a0 = xr[tk][0], a1 = xr[tk][1], a2 = xr[tk][2];
      d[tk] = a0.x * w0.x + a0.y * w0.y + a0.z * w0.z + a0.w * w0.w
            + a1.x * w1.x + a1.y * w1.y + a1.z * w1.z + a1.w * w1.w
            + a2.x * w2.x + a2.y * w2.y + a2.z * w2.z + a2.w * w2.w;
    }
#pragma unroll
    for (int m = 1; m < 64; m <<= 1){
#pragma unroll
      for (int tk = 0; tk < 4; tk++) d[tk] += __shfl_xor(d[tk], m, 64);
    }
    if (lane < 4) semv[wid][lane][cap] = d[lane] + sem_b[tt2 * 3 + c];
  }
  __syncthreads();

  if (lane < 12){
    const int tk = lane / 3, c = lane % 3;
    float v[10]; float sq = 0.f;
#pragma unroll
    for (int j = 0; j < 10; j++){ v[j] = semv[wid][tk][c * 10 + j]; sq += v[j] * v[j]; }
    sq += 1e-16f;
    const float scale = (sq / (1.f + sq)) / sqrtf(sq);
#pragma unroll
    for (int j = 0; j < 10; j++) semv[wid][tk][c * 10 + j] = v[j] * scale;
  }
  __syncthreads();

  if (lane < 12){
    const int tk = lane / 3, m = lane % 3;
    const int tt = t_ptr[0];
    float p[10][3];
#pragma unroll
    for (int r = 0; r < 10; r++){
      const float x0 = semv[wid][tk][r * 3 + 0];
      const float x1 = semv[wid][tk][r * 3 + 1];
      const float x2 = semv[wid][tk][r * 3 + 2];
      const float* rwp = rw + m * 90 + r * 9;
#pragma unroll
      for (int d = 0; d < 3; d++)
        p[r][d] = x0 * rwp[d] + x1 * rwp[3 + d] + x2 * rwp[6 + d];
    }
    float lg[10];
#pragma unroll
    for (int r = 0; r < 10; r++) lg[r] = 0.f;
    float v0 = 0.f, v1 = 0.f, v2 = 0.f;
    for (int it = 0; it < 3; ++it){
      float lr[10]; float mx = -3.0e38f;
#pragma unroll
      for (int r = 0; r < 10; r++){ lr[r] = (r <= tt) ? lg[r] : NEG_; mx = fmaxf(mx, lr[r]); }
      float e[10]; float sum = 0.f;
#pragma unroll
      for (int r = 0; r < 10; r++){ e[r] = expf(lr[r] - mx); sum += e[r]; }
      const float inv = 1.f / sum;
      v0 = 0.f; v1 = 0.f; v2 = 0.f;
#pragma unroll
      for (int r = 0; r < 10; r++){
        const float pr = e[r] * inv;
        v0 += pr * p[r][0]; v1 += pr * p[r][1]; v2 += pr * p[r][2];
      }
      if (it < 2){
        float sq = v0 * v0 + v1 * v1 + v2 * v2 + 1e-16f;
        float scale = (sq / (1.f + sq)) / sqrtf(sq);
        const float o0 = v0 * scale, o1 = v1 * scale, o2 = v2 * scale;
#pragma unroll
        for (int r = 0; r < 10; r++) lg[r] += p[r][0] * o0 + p[r][1] * o1 + p[r][2] * o2;
      }
    }
    float* dst = voteflat + (size_t)m * 49152 + (size_t)(tok0 + tk) * 3;
    dst[0] = v0; dst[1] = v1; dst[2] = v2;
  }
}

// ---------------- h_pre = x + (h_caps @ larger_w^T + b) * glarger  -> bf16 (vec4) -------
__global__ __launch_bounds__(256) void hpre_kernel(
    const float* __restrict__ x, const float* __restrict__ voteflat,
    const float* __restrict__ larger_w, const float* __restrict__ larger_b,
    const float* __restrict__ glarger, u16* __restrict__ hpre)
{
  size_t q = (size_t)blockIdx.x * 256 + threadIdx.x;   // 4 h-elems per thread
  if (q >= (size_t)16384 * 192) return;
  size_t n = q / 192;
  int h0 = (int)(q % 192) * 4;
  float vt[9];
#pragma unroll
  for (int m = 0; m < 3; m++)
#pragma unroll
    for (int c = 0; c < 3; c++)
      vt[m * 3 + c] = voteflat[(size_t)m * 49152 + n * 3 + c];
  float4 xv = *(const float4*)(x + n * 768 + h0);
  ushort4 ov;
  float xa[4] = {xv.x, xv.y, xv.z, xv.w};
  u16 oa[4];
#pragma unroll
  for (int j = 0; j < 4; j++){
    const int h = h0 + j;
    const float* lw = larger_w + (size_t)h * 9;
    float acc = larger_b[h];
#pragma unroll
    for (int k = 0; k < 9; k++) acc += vt[k] * lw[k];
    oa[j] = f2bf(xa[j] + acc * glarger[h]);
  }
  ov.x = oa[0]; ov.y = oa[1]; ov.z = oa[2]; ov.w = oa[3];
  *(ushort4*)(hpre + n * 768 + h0) = ov;
}

// ---------------- 256x256 8-phase bf16 MFMA GEMM, C = A(MxK) * B(NxK)^T -----------------
// m201 template, CLOBBER-FREE waits (no "memory" on s_waitcnt asm; raw s_barrier) so the
// compiler does NOT insert its own vmcnt(0) drains around the barriers.
// Stage schedule per K-tile j (race-free; ledger verified):
//   ph0: A-h0(j+1)  ph1: A-h1(j+1)  ph2: B-h0(j+2)  ph3: B-h1(j+2) + vmcnt(4)
// MODE 0: store bf16(gelu(acc+bias)*gate);  MODE 1: store f32 xres + gelu(acc+bias)*gate.
template<int MODE, int NDIM, int KDIM>
__global__ __launch_bounds__(512, 2) void gemm8(
    const u16* __restrict__ A, const u16* __restrict__ B,
    const float* __restrict__ bias, const float* __restrict__ gate,
    const float* __restrict__ xres, void* __restrict__ Cout, int NT_N)
{
  __shared__ __align__(16) u16 As[2][16384];   // [buf][half 128 rows x 64 k each]
  __shared__ __align__(16) u16 Bs[2][16384];
  constexpr int NT = KDIM / 64;

  const int nwg = (int)gridDim.x;              // multiple of 8
  const int cpx = nwg >> 3;
  const int wg  = ((int)blockIdx.x & 7) * cpx + ((int)blockIdx.x >> 3);
  const int bm = wg / NT_N, bn = wg % NT_N;
  const int m0 = bm * 256, n0 = bn * 256;
  const int tid = (int)threadIdx.x;
  const int w = tid >> 6, l = tid & 63;
  const int wr = w >> 2, wc = w & 3;           // 2 x 4 wave grid; wave tile 128 x 64

  f32x4 acc[8][4];
#pragma unroll
  for (int i = 0; i < 8; i++)
#pragma unroll
    for (int j = 0; j < 4; j++)
      acc[i][j] = (f32x4){0.f, 0.f, 0.f, 0.f};

  // stage one 128x64 half-tile (16KB): linear LDS dest, swizzled global source
  auto stage_half = [&](const u16* __restrict__ src, int r0, int k0, char* ldsbase){
#pragma unroll
    for (int jj = 0; jj < 2; ++jj){
      unsigned o  = (unsigned)(jj * 8192 + tid * 16);
      unsigned lo = swz(o);
      const u16* g = src + (size_t)(r0 + (int)(lo >> 7)) * KDIM + (k0 + (int)((lo & 127u) >> 1));
      async_load16(g, ldsbase + jj * 8192 + w * 1024);
    }
  };

  // prologue: A(0), B(0), B(1); keep B(1) (4 loads) in flight
  stage_half(A, m0,       0, (char*)As[0]);
  stage_half(A, m0 + 128, 0, (char*)As[0] + 16384);
  stage_half(B, n0,       0, (char*)Bs[0]);
  stage_half(B, n0 + 128, 0, (char*)Bs[0] + 16384);
  stage_half(B, n0,       64, (char*)Bs[1]);
  stage_half(B, n0 + 128, 64, (char*)Bs[1] + 16384);
  asm volatile("s_waitcnt vmcnt(4)");
  __builtin_amdgcn_sched_barrier(0);
  __builtin_amdgcn_s_barrier();

  for (int j = 0; j < NT; ++j){
    const int buf = j & 1;
    const char* abase = (const char*)As[buf] + wr * 16384;
    const char* bbase = (const char*)Bs[buf] + (wc >> 1) * 16384;
    bf16x8 bfr[4][2];
#pragma unroll
    for (int p = 0; p < 4; ++p){
      // --- ds reads for this phase ---
      if (p == 0){
#pragma unroll
        for (int g = 0; g < 4; ++g)
#pragma unroll
          for (int ks = 0; ks < 2; ++ks){
            unsigned o = (unsigned)((((wc & 1) * 64 + g * 16 + (l & 15)) << 7) + ks * 64 + ((l >> 4) << 4));
            bfr[g][ks] = *(const bf16x8*)(bbase + swz(o));
          }
      }
      bf16x8 afr[2][2];
#pragma unroll
      for (int fi = 0; fi < 2; ++fi)
#pragma unroll
        for (int ks = 0; ks < 2; ++ks){
          unsigned o = (unsigned)((((2 * p + fi) * 16 + (l & 15)) << 7) + ks * 64 + ((l >> 4) << 4));
          afr[fi][ks] = *(const bf16x8*)(abase + swz(o));
        }
      // --- stage one half-tile ---
      if (p == 0 && j + 1 < NT) stage_half(A, m0,       (j + 1) * 64, (char*)As[(j + 1) & 1]);
      if (p == 1 && j + 1 < NT) stage_half(A, m0 + 128, (j + 1) * 64, (char*)As[(j + 1) & 1] + 16384);
      if (p == 2 && j + 2 < NT) stage_half(B, n0,       (j + 2) * 64, (char*)Bs[buf]);
      if (p == 3 && j + 2 < NT) stage_half(B, n0 + 128, (j + 2) * 64, (char*)Bs[buf] + 16384);
      if (p == 3){
        if (j < NT - 2){
          asm volatile("s_waitcnt vmcnt(4)");
          __builtin_amdgcn_sched_barrier(0);
        } else if (j == NT - 2){
          asm volatile("s_waitcnt vmcnt(0)");
          __builtin_amdgcn_sched_barrier(0);
        }
      }
      __builtin_amdgcn_s_barrier();
      asm volatile("s_waitcnt lgkmcnt(0)");
      __builtin_amdgcn_sched_barrier(0);
      // --- 16 MFMA, ks-outer so consecutive MFMAs hit different accumulators ---
      __builtin_amdgcn_s_setprio(1);
#pragma unroll
      for (int ks = 0; ks < 2; ++ks)
#pragma unroll
        for (int fi = 0; fi < 2; ++fi)
#pragma unroll
          for (int g = 0; g < 4; ++g)
            acc[2 * p + fi][g] = __builtin_amdgcn_mfma_f32_16x16x32_bf16(
                afr[fi][ks], bfr[g][ks], acc[2 * p + fi][g], 0, 0, 0);
      __builtin_amdgcn_s_setprio(0);
      __builtin_amdgcn_s_barrier();
    }
  }

  // epilogue
#pragma unroll
  for (int f = 0; f < 8; ++f){
    const int rowb = m0 + wr * 128 + f * 16 + ((l >> 4) << 2);
#pragma unroll
    for (int g = 0; g < 4; ++g){
      const int col = n0 + wc * 64 + g * 16 + (l & 15);
      const float bv = bias[col], gv = gate[col];
#pragma unroll
      for (int j = 0; j < 4; ++j){
        const int row = rowb + j;
        float v = acc[f][g][j] + bv;
        float gl = gelu_exact(v) * gv;
        if (MODE == 0){
          ((u16*)Cout)[(size_t)row * NDIM + col] = f2bf(gl);
        } else {
          size_t off = (size_t)row * NDIM + col;
          ((float*)Cout)[off] = xres[off] + gl;
        }
      }
    }
  }
}

// ---------------- launcher ----------------
extern "C" void kernel_launch(void* const* d_in, const int* in_sizes, int n_in,
                              void* d_out, int out_size, void* d_ws, size_t ws_size,
                              hipStream_t stream)
{
  const float* x       = (const float*)d_in[0];
  const int*   t       = (const int*)  d_in[1];
  const float* s       = (const float*)d_in[2];
  const float* fc1_w   = (const float*)d_in[3];
  const float* fc1_b   = (const float*)d_in[4];
  const float* fc2_w   = (const float*)d_in[5];
  const float* fc2_b   = (const float*)d_in[6];
  const float* efc1    = (const float*)d_in[7];
  const float* efc2    = (const float*)d_in[8];
  const float* sem_w   = (const float*)d_in[9];
  const float* sem_b   = (const float*)d_in[10];
  const float* rw      = (const float*)d_in[11];
  const float* larger_w= (const float*)d_in[12];
  const float* larger_b= (const float*)d_in[13];
  const float* elarger = (const float*)d_in[14];

  char* ws = (char*)d_ws;
  float* vote    = (float*)(ws + 0);         //  589824 B  [3][16384][3] f32
  float* gfc1p   = (float*)(ws + 589824);    //    8192 B  [2048]
  float* b1p     = (float*)(ws + 598016);    //    8192 B  [2048]
  float* gfc2    = (float*)(ws + 606208);    //    3072 B  [768]
  float* glarger = (float*)(ws + 609280);    //    3072 B  [768]
  u16*   Bw1     = (u16*)  (ws + 612352);    // 3145728 B  [2048][768] bf16
  u16*   Bw2     = (u16*)  (ws + 3758080);   // 3145728 B  [768][2048] bf16
  u16*   hpre    = (u16*)  (ws + 6903808);   // 25165824 B [16384][768] bf16
  u16*   Hm      = (u16*)  (ws + 32069632);  // 67108864 B [16384][2048] bf16
  // total 99,178,496 B

  prep_gates<<<8, 256, 0, stream>>>(s, t, efc1, efc2, elarger, fc1_b, gfc1p, b1p, gfc2, glarger);
  conv_w1<<<1536, 256, 0, stream>>>(fc1_w, Bw1);
  conv_w2<<<1536, 256, 0, stream>>>(fc2_w, Bw2);
  sem_route<<<1024, 256, 0, stream>>>(x, t, sem_w, sem_b, rw, vote);
  hpre_kernel<<<12288, 256, 0, stream>>>(x, vote, larger_w, larger_b, glarger, hpre);
  gemm8<0, 2048, 768><<<512, 512, 0, stream>>>(hpre, Bw1, b1p, gfc1p, nullptr, (void*)Hm, 8);
  gemm8<1, 768, 2048><<<192, 512, 0, stream>>>(Hm, Bw2, fc2_b, gfc2, x, d_out, 3);
}

// Round 7
// 225.584 us; speedup vs baseline: 1.3103x; 1.1953x over previous
//
#include <hip/hip_runtime.h>
#include <stdint.h>
#include <math.h>

typedef unsigned short u16;
typedef __bf16 bf16x8 __attribute__((ext_vector_type(8)));
typedef float f32x4 __attribute__((ext_vector_type(4)));

#define NEG_ -10000.0f

__device__ __forceinline__ u16 f2bf(float f){
  unsigned u = __float_as_uint(f);
  unsigned r = (u + 0x7fffu + ((u >> 16) & 1u)) >> 16;
  return (u16)r;
}

// gelu exact via Abramowitz-Stegun 7.1.26 erf (|err| < 1.5e-7), ~14 VALU ops
__device__ __forceinline__ float gelu_exact(float v){
  float xe = v * 0.70710678118654752f;
  float ax = fabsf(xe);
  float k  = 1.0f / (1.0f + 0.3275911f * ax);
  float p  = ((((1.061405429f * k - 1.453152027f) * k + 1.421413741f) * k
               - 0.284496736f) * k + 0.254829592f) * k;
  float er = 1.0f - p * __expf(-ax * ax);
  er = copysignf(er, xe);
  return 0.5f * v * (1.0f + er);
}
__device__ __forceinline__ float sigmoidf_(float z){ return 1.f / (1.f + expf(-z)); }

__device__ __forceinline__ void async_load16(const void* g, void* lds){
  typedef const __attribute__((address_space(1))) unsigned int* gp_t;
  typedef __attribute__((address_space(3))) unsigned int* lp_t;
  __builtin_amdgcn_global_load_lds((gp_t)(uintptr_t)g, (lp_t)(uintptr_t)lds, 16, 0, 0);
}

__device__ __forceinline__ unsigned swz(unsigned o){ return o ^ ((o >> 3) & 0x70u); }

// ---------------- gates + padded bias ----------------
__global__ __launch_bounds__(256) void prep_gates(
    const float* __restrict__ s, const int* __restrict__ t,
    const float* __restrict__ efc1, const float* __restrict__ efc2,
    const float* __restrict__ elarger, const float* __restrict__ fc1_b,
    float* __restrict__ gfc1p, float* __restrict__ b1p,
    float* __restrict__ gfc2, float* __restrict__ glarger)
{
  int i = blockIdx.x * 256 + threadIdx.x;
  float sv = s[0]; int tt = t[0];
  if (i < 2048){
    float g = 0.f, b = 0.f;
    if (i < 2000){ g = sigmoidf_(sv * efc1[tt * 2000 + i]); b = fc1_b[i]; }
    gfc1p[i] = g; b1p[i] = b;
  }
  if (i < 768){
    gfc2[i]    = sigmoidf_(sv * efc2[tt * 768 + i]);
    glarger[i] = sigmoidf_(sv * elarger[tt * 768 + i]);
  }
}

// ---------------- weight conversions (zero-padded, vectorized) ----------------
__global__ __launch_bounds__(256) void conv_w1(const float* __restrict__ fc1_w, u16* __restrict__ Bw1){
  int q = blockIdx.x * 256 + threadIdx.x;              // 4 elems each, [2048][768]
  if (q >= 2048 * 192) return;
  int idx = q * 4;
  int n = idx / 768, k = idx % 768;
  ushort4 o;
  if (n < 2000){
    float4 v = *(const float4*)(fc1_w + (size_t)n * 768 + k);
    o.x = f2bf(v.x); o.y = f2bf(v.y); o.z = f2bf(v.z); o.w = f2bf(v.w);
  } else { o.x = o.y = o.z = o.w = 0; }
  *(ushort4*)(Bw1 + idx) = o;
}
__global__ __launch_bounds__(256) void conv_w2(const float* __restrict__ fc2_w, u16* __restrict__ Bw2){
  int q = blockIdx.x * 256 + threadIdx.x;              // 4 elems each, [768][2048]
  if (q >= 768 * 512) return;
  int idx = q * 4;
  int h = idx / 2048, k = idx % 2048;
  ushort4 o;
  if (k < 2000){                                        // 2000%4==0 -> whole float4 valid
    float4 v = *(const float4*)(fc2_w + (size_t)h * 2000 + k);
    o.x = f2bf(v.x); o.y = f2bf(v.y); o.z = f2bf(v.z); o.w = f2bf(v.w);
  } else { o.x = o.y = o.z = o.w = 0; }
  *(ushort4*)(Bw2 + idx) = o;
}

// ---------------- sem capsules + squash + routing + FUSED hpre -> bf16 ----------------
// 1 wave = 4 tokens; x rows stay in registers and feed both the capsule dots and the
// final h_pre = x + (h_caps @ larger_w^T + b) * glarger. Votes pass through LDS.
__global__ __launch_bounds__(256) void sem_route(
    const float* __restrict__ x, const int* __restrict__ t_ptr,
    const float* __restrict__ sem_w, const float* __restrict__ sem_b,
    const float* __restrict__ rw, const float* __restrict__ larger_w,
    const float* __restrict__ larger_b, const float* __restrict__ glarger,
    u16* __restrict__ hpre)
{
  __shared__ float semv[4][4][32];
  __shared__ float votes[4][4][9];   // [wave][token][m*3+c]
  const int tid  = threadIdx.x;
  const int wid  = tid >> 6, lane = tid & 63;
  const int tok0 = (blockIdx.x * 4 + wid) * 4;

  float4 xr[4][3];
#pragma unroll
  for (int tk = 0; tk < 4; tk++)
#pragma unroll
    for (int j = 0; j < 3; j++)
      xr[tk][j] = *(const float4*)(x + (size_t)(tok0 + tk) * 768 + j * 256 + lane * 4);

  for (int cap = 0; cap < 30; ++cap){
    const int c = cap / 10, tt2 = cap % 10;
    const float* wrow = sem_w + (size_t)(tt2 * 3 + c) * 768;
    const float4 w0 = *(const float4*)(wrow +       lane * 4);
    const float4 w1 = *(const float4*)(wrow + 256 + lane * 4);
    const float4 w2 = *(const float4*)(wrow + 512 + lane * 4);
    float d[4];
#pragma unroll
    for (int tk = 0; tk < 4; tk++){
      const float4 a0 = xr[tk][0], a1 = xr[tk][1], a2 = xr[tk][2];
      d[tk] = a0.x * w0.x + a0.y * w0.y + a0.z * w0.z + a0.w * w0.w
            + a1.x * w1.x + a1.y * w1.y + a1.z * w1.z + a1.w * w1.w
            + a2.x * w2.x + a2.y * w2.y + a2.z * w2.z + a2.w * w2.w;
    }
#pragma unroll
    for (int m = 1; m < 64; m <<= 1){
#pragma unroll
      for (int tk = 0; tk < 4; tk++) d[tk] += __shfl_xor(d[tk], m, 64);
    }
    if (lane < 4) semv[wid][lane][cap] = d[lane] + sem_b[tt2 * 3 + c];
  }
  __syncthreads();

  if (lane < 12){
    const int tk = lane / 3, c = lane % 3;
    float v[10]; float sq = 0.f;
#pragma unroll
    for (int j = 0; j < 10; j++){ v[j] = semv[wid][tk][c * 10 + j]; sq += v[j] * v[j]; }
    sq += 1e-16f;
    const float scale = (sq / (1.f + sq)) / sqrtf(sq);
#pragma unroll
    for (int j = 0; j < 10; j++) semv[wid][tk][c * 10 + j] = v[j] * scale;
  }
  __syncthreads();

  if (lane < 12){
    const int tk = lane / 3, m = lane % 3;
    const int tt = t_ptr[0];
    float p[10][3];
#pragma unroll
    for (int r = 0; r < 10; r++){
      const float x0 = semv[wid][tk][r * 3 + 0];
      const float x1 = semv[wid][tk][r * 3 + 1];
      const float x2 = semv[wid][tk][r * 3 + 2];
      const float* rwp = rw + m * 90 + r * 9;
#pragma unroll
      for (int d = 0; d < 3; d++)
        p[r][d] = x0 * rwp[d] + x1 * rwp[3 + d] + x2 * rwp[6 + d];
    }
    float lg[10];
#pragma unroll
    for (int r = 0; r < 10; r++) lg[r] = 0.f;
    float v0 = 0.f, v1 = 0.f, v2 = 0.f;
    for (int it = 0; it < 3; ++it){
      float lr[10]; float mx = -3.0e38f;
#pragma unroll
      for (int r = 0; r < 10; r++){ lr[r] = (r <= tt) ? lg[r] : NEG_; mx = fmaxf(mx, lr[r]); }
      float e[10]; float sum = 0.f;
#pragma unroll
      for (int r = 0; r < 10; r++){ e[r] = expf(lr[r] - mx); sum += e[r]; }
      const float inv = 1.f / sum;
      v0 = 0.f; v1 = 0.f; v2 = 0.f;
#pragma unroll
      for (int r = 0; r < 10; r++){
        const float pr = e[r] * inv;
        v0 += pr * p[r][0]; v1 += pr * p[r][1]; v2 += pr * p[r][2];
      }
      if (it < 2){
        float sq = v0 * v0 + v1 * v1 + v2 * v2 + 1e-16f;
        float scale = (sq / (1.f + sq)) / sqrtf(sq);
        const float o0 = v0 * scale, o1 = v1 * scale, o2 = v2 * scale;
#pragma unroll
        for (int r = 0; r < 10; r++) lg[r] += p[r][0] * o0 + p[r][1] * o1 + p[r][2] * o2;
      }
    }
    votes[wid][tk][m * 3 + 0] = v0;
    votes[wid][tk][m * 3 + 1] = v1;
    votes[wid][tk][m * 3 + 2] = v2;
  }
  __syncthreads();

  // ---- fused hpre: all 64 lanes; lane owns h = jq*256 + lane*4 .. +3 ----
  float vt[4][9];
#pragma unroll
  for (int tk = 0; tk < 4; tk++)
#pragma unroll
    for (int k = 0; k < 9; k++)
      vt[tk][k] = votes[wid][tk][k];

#pragma unroll
  for (int jq = 0; jq < 3; ++jq){
    const int h0 = jq * 256 + lane * 4;
    const float4* lwq = (const float4*)(larger_w + (size_t)h0 * 9);  // 36 consecutive floats
    float lw36[36];
#pragma unroll
    for (int k = 0; k < 9; k++){
      float4 tq = lwq[k];
      lw36[4*k] = tq.x; lw36[4*k+1] = tq.y; lw36[4*k+2] = tq.z; lw36[4*k+3] = tq.w;
    }
    const float4 bq = *(const float4*)(larger_b + h0);
    const float4 gq = *(const float4*)(glarger + h0);
    const float bb[4] = {bq.x, bq.y, bq.z, bq.w};
    const float gg[4] = {gq.x, gq.y, gq.z, gq.w};
#pragma unroll
    for (int tk = 0; tk < 4; ++tk){
      const float xa[4] = {xr[tk][jq].x, xr[tk][jq].y, xr[tk][jq].z, xr[tk][jq].w};
      u16 oa[4];
#pragma unroll
      for (int r = 0; r < 4; ++r){
        float a = bb[r];
#pragma unroll
        for (int k = 0; k < 9; ++k) a += vt[tk][k] * lw36[r * 9 + k];
        oa[r] = f2bf(xa[r] + a * gg[r]);
      }
      ushort4 ov; ov.x = oa[0]; ov.y = oa[1]; ov.z = oa[2]; ov.w = oa[3];
      *(ushort4*)(hpre + (size_t)(tok0 + tk) * 768 + h0) = ov;
    }
  }
}

// ---------------- 128x128 bf16 MFMA GEMM, C = A(MxK) * B(NxK)^T, 2 blocks/CU ------------
// 64KB LDS double-buffer -> 2 co-resident blocks desynchronize phases (m114 mechanism).
// Per K-tile j, 2 phases of 16 MFMA; counted-vmcnt ledger (never 0 in main loop):
//   ph0: read all B-frags + A-frags(fm0,1); stage A(j+1) -> As[(j+1)&1]
//   ph1: read A-frags(fm2,3); stage B(j+2) -> Bs[j&1]; vmcnt(4)
// Clobber-free waits; T1 XCD swizzle; T2 LDS XOR swizzle; T5 setprio.
// MODE 0: store bf16(gelu(acc+bias)*gate);  MODE 1: store f32 xres + gelu(acc+bias)*gate.
template<int MODE, int NDIM, int KDIM>
__global__ __launch_bounds__(256, 2) void gemm128(
    const u16* __restrict__ A, const u16* __restrict__ B,
    const float* __restrict__ bias, const float* __restrict__ gate,
    const float* __restrict__ xres, void* __restrict__ Cout, int NT_N)
{
  __shared__ __align__(16) u16 As[2][8192];   // [buf][128 rows x 64 k]
  __shared__ __align__(16) u16 Bs[2][8192];
  constexpr int NT = KDIM / 64;

  const int nwg = (int)gridDim.x;              // multiple of 8
  const int cpx = nwg >> 3;
  const int wg  = ((int)blockIdx.x & 7) * cpx + ((int)blockIdx.x >> 3);
  const int bm = wg / NT_N, bn = wg % NT_N;
  const int m0 = bm * 128, n0 = bn * 128;
  const int tid = (int)threadIdx.x;
  const int w = tid >> 6, l = tid & 63;
  const int wr = w >> 1, wc = w & 1;           // 2 x 2 wave grid; wave tile 64 x 64

  f32x4 acc[4][4];
#pragma unroll
  for (int i = 0; i < 4; i++)
#pragma unroll
    for (int j = 0; j < 4; j++)
      acc[i][j] = (f32x4){0.f, 0.f, 0.f, 0.f};

  // stage one 128x64 tile (16KB): linear LDS dest, swizzled global source
  auto stage_tile = [&](const u16* __restrict__ src, int r0, int k0, u16* lds){
#pragma unroll
    for (int jj = 0; jj < 4; ++jj){
      unsigned o  = (unsigned)(jj * 4096 + tid * 16);
      unsigned lo = swz(o);
      const u16* g = src + (size_t)(r0 + (int)(lo >> 7)) * KDIM + (k0 + (int)((lo & 127u) >> 1));
      async_load16(g, (char*)lds + jj * 4096 + w * 1024);
    }
  };

  // prologue: A(0), B(0), B(1); keep B(1) (4 loads) in flight
  stage_tile(A, m0, 0,  As[0]);
  stage_tile(B, n0, 0,  Bs[0]);
  stage_tile(B, n0, 64, Bs[1]);
  asm volatile("s_waitcnt vmcnt(4)");
  __builtin_amdgcn_sched_barrier(0);
  __builtin_amdgcn_s_barrier();

#pragma unroll 2
  for (int j = 0; j < NT; ++j){
    const int buf = j & 1;
    const char* abase = (const char*)As[buf];
    const char* bbase = (const char*)Bs[buf];
    bf16x8 bfr[4][2];
#pragma unroll
    for (int p = 0; p < 2; ++p){
      if (p == 0){
#pragma unroll
        for (int g = 0; g < 4; ++g)
#pragma unroll
          for (int ks = 0; ks < 2; ++ks){
            unsigned o = (unsigned)(((wc * 64 + g * 16 + (l & 15)) << 7) + ks * 64 + ((l >> 4) << 4));
            bfr[g][ks] = *(const bf16x8*)(bbase + swz(o));
          }
      }
      bf16x8 afr[2][2];
#pragma unroll
      for (int fi = 0; fi < 2; ++fi)
#pragma unroll
        for (int ks = 0; ks < 2; ++ks){
          unsigned o = (unsigned)(((wr * 64 + (2 * p + fi) * 16 + (l & 15)) << 7) + ks * 64 + ((l >> 4) << 4));
          afr[fi][ks] = *(const bf16x8*)(abase + swz(o));
        }
      if (p == 0 && j + 1 < NT) stage_tile(A, m0, (j + 1) * 64, As[(j + 1) & 1]);
      if (p == 1 && j + 2 < NT) stage_tile(B, n0, (j + 2) * 64, Bs[buf]);
      if (p == 1){
        if (j < NT - 2){
          asm volatile("s_waitcnt vmcnt(4)");
          __builtin_amdgcn_sched_barrier(0);
        } else if (j == NT - 2){
          asm volatile("s_waitcnt vmcnt(0)");
          __builtin_amdgcn_sched_barrier(0);
        }
      }
      __builtin_amdgcn_s_barrier();
      asm volatile("s_waitcnt lgkmcnt(0)");
      __builtin_amdgcn_sched_barrier(0);
      __builtin_amdgcn_s_setprio(1);
#pragma unroll
      for (int ks = 0; ks < 2; ++ks)
#pragma unroll
        for (int fi = 0; fi < 2; ++fi)
#pragma unroll
          for (int g = 0; g < 4; ++g)
            acc[2 * p + fi][g] = __builtin_amdgcn_mfma_f32_16x16x32_bf16(
                afr[fi][ks], bfr[g][ks], acc[2 * p + fi][g], 0, 0, 0);
      __builtin_amdgcn_s_setprio(0);
      __builtin_amdgcn_s_barrier();
    }
  }

  // epilogue
#pragma unroll
  for (int f = 0; f < 4; ++f){
    const int rowb = m0 + wr * 64 + f * 16 + ((l >> 4) << 2);
#pragma unroll
    for (int g = 0; g < 4; ++g){
      const int col = n0 + wc * 64 + g * 16 + (l & 15);
      const float bv = bias[col], gv = gate[col];
#pragma unroll
      for (int j = 0; j < 4; ++j){
        const int row = rowb + j;
        float v = acc[f][g][j] + bv;
        float gl = gelu_exact(v) * gv;
        if (MODE == 0){
          ((u16*)Cout)[(size_t)row * NDIM + col] = f2bf(gl);
        } else {
          size_t off = (size_t)row * NDIM + col;
          ((float*)Cout)[off] = xres[off] + gl;
        }
      }
    }
  }
}

// ---------------- launcher ----------------
extern "C" void kernel_launch(void* const* d_in, const int* in_sizes, int n_in,
                              void* d_out, int out_size, void* d_ws, size_t ws_size,
                              hipStream_t stream)
{
  const float* x       = (const float*)d_in[0];
  const int*   t       = (const int*)  d_in[1];
  const float* s       = (const float*)d_in[2];
  const float* fc1_w   = (const float*)d_in[3];
  const float* fc1_b   = (const float*)d_in[4];
  const float* fc2_w   = (const float*)d_in[5];
  const float* fc2_b   = (const float*)d_in[6];
  const float* efc1    = (const float*)d_in[7];
  const float* efc2    = (const float*)d_in[8];
  const float* sem_w   = (const float*)d_in[9];
  const float* sem_b   = (const float*)d_in[10];
  const float* rw      = (const float*)d_in[11];
  const float* larger_w= (const float*)d_in[12];
  const float* larger_b= (const float*)d_in[13];
  const float* elarger = (const float*)d_in[14];

  char* ws = (char*)d_ws;
  float* gfc1p   = (float*)(ws + 0);         //    8192 B  [2048]
  float* b1p     = (float*)(ws + 8192);      //    8192 B  [2048]
  float* gfc2    = (float*)(ws + 16384);     //    3072 B  [768]
  float* glarger = (float*)(ws + 19456);     //    3072 B  [768]
  u16*   Bw1     = (u16*)  (ws + 22528);     // 3145728 B  [2048][768] bf16
  u16*   Bw2     = (u16*)  (ws + 3168256);   // 3145728 B  [768][2048] bf16
  u16*   hpre    = (u16*)  (ws + 6313984);   // 25165824 B [16384][768] bf16
  u16*   Hm      = (u16*)  (ws + 31479808);  // 67108864 B [16384][2048] bf16
  // total 98,588,672 B

  prep_gates<<<8, 256, 0, stream>>>(s, t, efc1, efc2, elarger, fc1_b, gfc1p, b1p, gfc2, glarger);
  conv_w1<<<1536, 256, 0, stream>>>(fc1_w, Bw1);
  conv_w2<<<1536, 256, 0, stream>>>(fc2_w, Bw2);
  sem_route<<<1024, 256, 0, stream>>>(x, t, sem_w, sem_b, rw, larger_w, larger_b, glarger, hpre);
  gemm128<0, 2048, 768><<<2048, 256, 0, stream>>>(hpre, Bw1, b1p, gfc1p, nullptr, (void*)Hm, 16);
  gemm128<1, 768, 2048><<<768, 256, 0, stream>>>(Hm, Bw2, fc2_b, gfc2, x, d_out, 6);
}

// Round 8
// 185.765 us; speedup vs baseline: 1.5912x; 1.2144x over previous
//
#include <hip/hip_runtime.h>
#include <stdint.h>
#include <math.h>

typedef unsigned short u16;
typedef __bf16 bf16x8 __attribute__((ext_vector_type(8)));
typedef u16 u16x8 __attribute__((ext_vector_type(8)));
typedef u16 u16x4 __attribute__((ext_vector_type(4)));
typedef float f32x4 __attribute__((ext_vector_type(4)));

#define NEG_ -10000.0f

__device__ __forceinline__ u16 f2bf(float f){
  unsigned u = __float_as_uint(f);
  unsigned r = (u + 0x7fffu + ((u >> 16) & 1u)) >> 16;
  return (u16)r;
}
__device__ __forceinline__ float bf2f(u16 v){
  return __uint_as_float(((unsigned)v) << 16);
}

// gelu exact via Abramowitz-Stegun 7.1.26 erf (|err| < 1.5e-7), ~14 VALU ops
__device__ __forceinline__ float gelu_exact(float v){
  float xe = v * 0.70710678118654752f;
  float ax = fabsf(xe);
  float k  = 1.0f / (1.0f + 0.3275911f * ax);
  float p  = ((((1.061405429f * k - 1.453152027f) * k + 1.421413741f) * k
               - 0.284496736f) * k + 0.254829592f) * k;
  float er = 1.0f - p * __expf(-ax * ax);
  er = copysignf(er, xe);
  return 0.5f * v * (1.0f + er);
}
__device__ __forceinline__ float sigmoidf_(float z){ return 1.f / (1.f + expf(-z)); }

__device__ __forceinline__ void async_load16(const void* g, void* lds){
  typedef const __attribute__((address_space(1))) unsigned int* gp_t;
  typedef __attribute__((address_space(3))) unsigned int* lp_t;
  __builtin_amdgcn_global_load_lds((gp_t)(uintptr_t)g, (lp_t)(uintptr_t)lds, 16, 0, 0);
}

__device__ __forceinline__ unsigned swz(unsigned o){ return o ^ ((o >> 3) & 0x70u); }

// ---------------- gates + padded bias ----------------
__global__ __launch_bounds__(256) void prep_gates(
    const float* __restrict__ s, const int* __restrict__ t,
    const float* __restrict__ efc1, const float* __restrict__ efc2,
    const float* __restrict__ elarger, const float* __restrict__ fc1_b,
    float* __restrict__ gfc1p, float* __restrict__ b1p,
    float* __restrict__ gfc2, float* __restrict__ glarger)
{
  int i = blockIdx.x * 256 + threadIdx.x;
  float sv = s[0]; int tt = t[0];
  if (i < 2048){
    float g = 0.f, b = 0.f;
    if (i < 2000){ g = sigmoidf_(sv * efc1[tt * 2000 + i]); b = fc1_b[i]; }
    gfc1p[i] = g; b1p[i] = b;
  }
  if (i < 768){
    gfc2[i]    = sigmoidf_(sv * efc2[tt * 768 + i]);
    glarger[i] = sigmoidf_(sv * elarger[tt * 768 + i]);
  }
}

// ---------------- weight conversions (zero-padded, vectorized) ----------------
__global__ __launch_bounds__(256) void conv_w1(const float* __restrict__ fc1_w, u16* __restrict__ Bw1){
  int q = blockIdx.x * 256 + threadIdx.x;              // 4 elems each, [2048][768]
  if (q >= 2048 * 192) return;
  int idx = q * 4;
  int n = idx / 768, k = idx % 768;
  ushort4 o;
  if (n < 2000){
    float4 v = *(const float4*)(fc1_w + (size_t)n * 768 + k);
    o.x = f2bf(v.x); o.y = f2bf(v.y); o.z = f2bf(v.z); o.w = f2bf(v.w);
  } else { o.x = o.y = o.z = o.w = 0; }
  *(ushort4*)(Bw1 + idx) = o;
}
__global__ __launch_bounds__(256) void conv_w2(const float* __restrict__ fc2_w, u16* __restrict__ Bw2){
  int q = blockIdx.x * 256 + threadIdx.x;              // 4 elems each, [768][2048]
  if (q >= 768 * 512) return;
  int idx = q * 4;
  int h = idx / 2048, k = idx % 2048;
  ushort4 o;
  if (k < 2000){                                        // 2000%4==0 -> whole float4 valid
    float4 v = *(const float4*)(fc2_w + (size_t)h * 2000 + k);
    o.x = f2bf(v.x); o.y = f2bf(v.y); o.z = f2bf(v.z); o.w = f2bf(v.w);
  } else { o.x = o.y = o.z = o.w = 0; }
  *(ushort4*)(Bw2 + idx) = o;
}

// ---------------- sem capsules (MFMA) + squash + routing + hpre, fully fused ----------
// 512 blocks x 256 threads; 32 tokens/block.
// Phase 1: x(32x768) f32->bf16 into swizzled LDS subtiles [12][32][64]; sem_w staged
//          per K-step; 4 waves each MFMA a 16-token x 16-cap quadrant (24 mfma).
// Phase 2: squash + dynamic routing per (token, m) on 96 threads -> votes LDS.
// Phase 3: hpre = bf16( x_bf16 + (votes @ larger_w^T + b) * glarger ), x read from LDS.
__global__ __launch_bounds__(256) void sem_route(
    const float* __restrict__ x, const int* __restrict__ t_ptr,
    const float* __restrict__ sem_w, const float* __restrict__ sem_b,
    const float* __restrict__ rw, const float* __restrict__ larger_w,
    const float* __restrict__ larger_b, const float* __restrict__ glarger,
    u16* __restrict__ hpre)
{
  __shared__ __align__(16) u16 xbf[12 * 32 * 64];   // 49152 B, 12 subtiles of [32][64]
  __shared__ __align__(16) u16 wlds[2 * 32 * 64];   //  8192 B, double-buffered [32][64]
  __shared__ float semv_s[32][32];                  //  4096 B
  __shared__ float votes_s[32][9];                  //  1152 B

  const int tid  = (int)threadIdx.x;
  const int w    = tid >> 6, l = tid & 63;
  const int tok0 = (int)blockIdx.x * 32;

  // ---- stage x: 12 subtiles, reg-staged f32->bf16, T2-swizzled writes ----
  {
    const int r = tid >> 3;            // 0..31 token row
    const int kq = (tid & 7) * 8;      // 8 k-elems
    const float* xrow = x + (size_t)(tok0 + r) * 768 + kq;
#pragma unroll
    for (int j = 0; j < 12; ++j){
      float4 v0 = *(const float4*)(xrow + j * 64);
      float4 v1 = *(const float4*)(xrow + j * 64 + 4);
      u16x8 pk;
      pk[0] = f2bf(v0.x); pk[1] = f2bf(v0.y); pk[2] = f2bf(v0.z); pk[3] = f2bf(v0.w);
      pk[4] = f2bf(v1.x); pk[5] = f2bf(v1.y); pk[6] = f2bf(v1.z); pk[7] = f2bf(v1.w);
      unsigned o = (unsigned)(((j * 32 + r) << 7) + kq * 2);
      *(u16x8*)((char*)xbf + swz(o)) = pk;
    }
    // stage w subtile 0 into buf 0 (rows 30,31 zero)
    u16x8 pw = (u16x8)(u16)0;
    if (r < 30){
      const float* wr_ = sem_w + (size_t)r * 768 + kq;
      float4 v0 = *(const float4*)(wr_);
      float4 v1 = *(const float4*)(wr_ + 4);
      pw[0] = f2bf(v0.x); pw[1] = f2bf(v0.y); pw[2] = f2bf(v0.z); pw[3] = f2bf(v0.w);
      pw[4] = f2bf(v1.x); pw[5] = f2bf(v1.y); pw[6] = f2bf(v1.z); pw[7] = f2bf(v1.w);
    }
    unsigned ow = (unsigned)((r << 7) + kq * 2);
    *(u16x8*)((char*)wlds + swz(ow)) = pw;
  }
  __syncthreads();

  // ---- MFMA projection: wave w -> token rows (w>>1)*16, caps (w&1)*16 ----
  const int rowblk = (w >> 1) * 16, nb = (w & 1) * 16;
  f32x4 acc = (f32x4){0.f, 0.f, 0.f, 0.f};
  for (int j = 0; j < 12; ++j){
    const int buf = j & 1;
    bf16x8 af[2], bf[2];
#pragma unroll
    for (int ks = 0; ks < 2; ++ks){
      unsigned oa = (unsigned)(((j * 32 + rowblk + (l & 15)) << 7) + ks * 64 + ((l >> 4) << 4));
      af[ks] = *(const bf16x8*)((const char*)xbf + swz(oa));
      unsigned ob = (unsigned)(((buf * 32 + nb + (l & 15)) << 7) + ks * 64 + ((l >> 4) << 4));
      bf[ks] = *(const bf16x8*)((const char*)wlds + swz(ob));
    }
    // stage w subtile j+1 into the other buffer
    if (j + 1 < 12){
      const int r = tid >> 3, kq = (tid & 7) * 8;
      u16x8 pw = (u16x8)(u16)0;
      if (r < 30){
        const float* wr_ = sem_w + (size_t)r * 768 + (j + 1) * 64 + kq;
        float4 v0 = *(const float4*)(wr_);
        float4 v1 = *(const float4*)(wr_ + 4);
        pw[0] = f2bf(v0.x); pw[1] = f2bf(v0.y); pw[2] = f2bf(v0.z); pw[3] = f2bf(v0.w);
        pw[4] = f2bf(v1.x); pw[5] = f2bf(v1.y); pw[6] = f2bf(v1.z); pw[7] = f2bf(v1.w);
      }
      unsigned ow = (unsigned)(((((j + 1) & 1) * 32 + r) << 7) + kq * 2);
      *(u16x8*)((char*)wlds + swz(ow)) = pw;
    }
#pragma unroll
    for (int ks = 0; ks < 2; ++ks)
      acc = __builtin_amdgcn_mfma_f32_16x16x32_bf16(af[ks], bf[ks], acc, 0, 0, 0);
    __syncthreads();
  }
  // C layout: col = lane&15 (cap), row = (lane>>4)*4 + j (token within 16-block)
#pragma unroll
  for (int jj = 0; jj < 4; ++jj)
    semv_s[rowblk + (l >> 4) * 4 + jj][nb + (l & 15)] = acc[jj];
  __syncthreads();

  // ---- squash + dynamic routing per (token, m); 96 active threads ----
  if (tid < 96){
    const int tk = tid & 31, m = tid >> 5;
    const int tt = t_ptr[0];
    float s30[30];
#pragma unroll
    for (int jf = 0; jf < 30; ++jf){
      const int c = jf / 10, tcap = jf % 10;
      const int wrow = tcap * 3 + c;
      s30[jf] = semv_s[tk][wrow] + sem_b[wrow];
    }
#pragma unroll
    for (int c = 0; c < 3; ++c){
      float sq = 0.f;
#pragma unroll
      for (int jf = 0; jf < 10; ++jf){ float v = s30[c * 10 + jf]; sq += v * v; }
      sq += 1e-16f;
      const float scale = (sq / (1.f + sq)) / sqrtf(sq);
#pragma unroll
      for (int jf = 0; jf < 10; ++jf) s30[c * 10 + jf] *= scale;
    }
    float p[10][3];
#pragma unroll
    for (int r = 0; r < 10; r++){
      const float x0 = s30[r * 3 + 0], x1 = s30[r * 3 + 1], x2 = s30[r * 3 + 2];
      const float* rwp = rw + m * 90 + r * 9;
#pragma unroll
      for (int d = 0; d < 3; d++)
        p[r][d] = x0 * rwp[d] + x1 * rwp[3 + d] + x2 * rwp[6 + d];
    }
    float lg[10];
#pragma unroll
    for (int r = 0; r < 10; r++) lg[r] = 0.f;
    float v0 = 0.f, v1 = 0.f, v2 = 0.f;
    for (int it = 0; it < 3; ++it){
      float lr[10]; float mx = -3.0e38f;
#pragma unroll
      for (int r = 0; r < 10; r++){ lr[r] = (r <= tt) ? lg[r] : NEG_; mx = fmaxf(mx, lr[r]); }
      float e[10]; float sum = 0.f;
#pragma unroll
      for (int r = 0; r < 10; r++){ e[r] = expf(lr[r] - mx); sum += e[r]; }
      const float inv = 1.f / sum;
      v0 = 0.f; v1 = 0.f; v2 = 0.f;
#pragma unroll
      for (int r = 0; r < 10; r++){
        const float pr = e[r] * inv;
        v0 += pr * p[r][0]; v1 += pr * p[r][1]; v2 += pr * p[r][2];
      }
      if (it < 2){
        float sq = v0 * v0 + v1 * v1 + v2 * v2 + 1e-16f;
        float scale = (sq / (1.f + sq)) / sqrtf(sq);
        const float o0 = v0 * scale, o1 = v1 * scale, o2 = v2 * scale;
#pragma unroll
        for (int r = 0; r < 10; r++) lg[r] += p[r][0] * o0 + p[r][1] * o1 + p[r][2] * o2;
      }
    }
    votes_s[tk][m * 3 + 0] = v0;
    votes_s[tk][m * 3 + 1] = v1;
    votes_s[tk][m * 3 + 2] = v2;
  }
  __syncthreads();

  // ---- hpre: 192 threads, thread = h-quad q; x read back from LDS (bf16) ----
  if (tid < 192){
    const int q = tid, h0 = q * 4;
    float lw36[36];
    const float4* lwq = (const float4*)(larger_w + (size_t)h0 * 9);
#pragma unroll
    for (int k = 0; k < 9; k++){
      float4 tq = lwq[k];
      lw36[4*k] = tq.x; lw36[4*k+1] = tq.y; lw36[4*k+2] = tq.z; lw36[4*k+3] = tq.w;
    }
    const float4 bq = *(const float4*)(larger_b + h0);
    const float4 gq = *(const float4*)(glarger + h0);
    const float bb[4] = {bq.x, bq.y, bq.z, bq.w};
    const float gg[4] = {gq.x, gq.y, gq.z, gq.w};
    const int kstep = h0 >> 6, col = h0 & 63;
    for (int tk = 0; tk < 32; ++tk){
      float vt[9];
#pragma unroll
      for (int k = 0; k < 9; k++) vt[k] = votes_s[tk][k];
      unsigned o = (unsigned)(((kstep * 32 + tk) << 7) + col * 2);
      u16x4 xb = *(const u16x4*)((const char*)xbf + swz(o));
      u16 oa[4];
#pragma unroll
      for (int r = 0; r < 4; ++r){
        float a = bb[r];
#pragma unroll
        for (int k = 0; k < 9; ++k) a += vt[k] * lw36[r * 9 + k];
        oa[r] = f2bf(bf2f(xb[r]) + a * gg[r]);
      }
      ushort4 ov; ov.x = oa[0]; ov.y = oa[1]; ov.z = oa[2]; ov.w = oa[3];
      *(ushort4*)(hpre + (size_t)(tok0 + tk) * 768 + h0) = ov;
    }
  }
}

// ---------------- 128x128 bf16 MFMA GEMM, C = A(MxK) * B(NxK)^T, 2 blocks/CU ------------
// 64KB LDS double-buffer -> 2 co-resident blocks desynchronize phases (m114 mechanism).
// Per K-tile j, 2 phases of 16 MFMA; counted-vmcnt ledger (never 0 in main loop):
//   ph0: read all B-frags + A-frags(fm0,1); stage A(j+1) -> As[(j+1)&1]
//   ph1: read A-frags(fm2,3); stage B(j+2) -> Bs[j&1]; vmcnt(4)
// Clobber-free waits; T1 XCD swizzle; T2 LDS XOR swizzle; T5 setprio.
// MODE 0: store bf16(gelu(acc+bias)*gate);  MODE 1: store f32 xres + gelu(acc+bias)*gate.
template<int MODE, int NDIM, int KDIM>
__global__ __launch_bounds__(256, 2) void gemm128(
    const u16* __restrict__ A, const u16* __restrict__ B,
    const float* __restrict__ bias, const float* __restrict__ gate,
    const float* __restrict__ xres, void* __restrict__ Cout, int NT_N)
{
  __shared__ __align__(16) u16 As[2][8192];   // [buf][128 rows x 64 k]
  __shared__ __align__(16) u16 Bs[2][8192];
  constexpr int NT = KDIM / 64;

  const int nwg = (int)gridDim.x;              // multiple of 8
  const int cpx = nwg >> 3;
  const int wg  = ((int)blockIdx.x & 7) * cpx + ((int)blockIdx.x >> 3);
  const int bm = wg / NT_N, bn = wg % NT_N;
  const int m0 = bm * 128, n0 = bn * 128;
  const int tid = (int)threadIdx.x;
  const int w = tid >> 6, l = tid & 63;
  const int wr = w >> 1, wc = w & 1;           // 2 x 2 wave grid; wave tile 64 x 64

  f32x4 acc[4][4];
#pragma unroll
  for (int i = 0; i < 4; i++)
#pragma unroll
    for (int j = 0; j < 4; j++)
      acc[i][j] = (f32x4){0.f, 0.f, 0.f, 0.f};

  // stage one 128x64 tile (16KB): linear LDS dest, swizzled global source
  auto stage_tile = [&](const u16* __restrict__ src, int r0, int k0, u16* lds){
#pragma unroll
    for (int jj = 0; jj < 4; ++jj){
      unsigned o  = (unsigned)(jj * 4096 + tid * 16);
      unsigned lo = swz(o);
      const u16* g = src + (size_t)(r0 + (int)(lo >> 7)) * KDIM + (k0 + (int)((lo & 127u) >> 1));
      async_load16(g, (char*)lds + jj * 4096 + w * 1024);
    }
  };

  // prologue: A(0), B(0), B(1); keep B(1) (4 loads) in flight
  stage_tile(A, m0, 0,  As[0]);
  stage_tile(B, n0, 0,  Bs[0]);
  stage_tile(B, n0, 64, Bs[1]);
  asm volatile("s_waitcnt vmcnt(4)");
  __builtin_amdgcn_sched_barrier(0);
  __builtin_amdgcn_s_barrier();

#pragma unroll 2
  for (int j = 0; j < NT; ++j){
    const int buf = j & 1;
    const char* abase = (const char*)As[buf];
    const char* bbase = (const char*)Bs[buf];
    bf16x8 bfr[4][2];
#pragma unroll
    for (int p = 0; p < 2; ++p){
      if (p == 0){
#pragma unroll
        for (int g = 0; g < 4; ++g)
#pragma unroll
          for (int ks = 0; ks < 2; ++ks){
            unsigned o = (unsigned)(((wc * 64 + g * 16 + (l & 15)) << 7) + ks * 64 + ((l >> 4) << 4));
            bfr[g][ks] = *(const bf16x8*)(bbase + swz(o));
          }
      }
      bf16x8 afr[2][2];
#pragma unroll
      for (int fi = 0; fi < 2; ++fi)
#pragma unroll
        for (int ks = 0; ks < 2; ++ks){
          unsigned o = (unsigned)(((wr * 64 + (2 * p + fi) * 16 + (l & 15)) << 7) + ks * 64 + ((l >> 4) << 4));
          afr[fi][ks] = *(const bf16x8*)(abase + swz(o));
        }
      if (p == 0 && j + 1 < NT) stage_tile(A, m0, (j + 1) * 64, As[(j + 1) & 1]);
      if (p == 1 && j + 2 < NT) stage_tile(B, n0, (j + 2) * 64, Bs[buf]);
      if (p == 1){
        if (j < NT - 2){
          asm volatile("s_waitcnt vmcnt(4)");
          __builtin_amdgcn_sched_barrier(0);
        } else if (j == NT - 2){
          asm volatile("s_waitcnt vmcnt(0)");
          __builtin_amdgcn_sched_barrier(0);
        }
      }
      __builtin_amdgcn_s_barrier();
      asm volatile("s_waitcnt lgkmcnt(0)");
      __builtin_amdgcn_sched_barrier(0);
      __builtin_amdgcn_s_setprio(1);
#pragma unroll
      for (int ks = 0; ks < 2; ++ks)
#pragma unroll
        for (int fi = 0; fi < 2; ++fi)
#pragma unroll
          for (int g = 0; g < 4; ++g)
            acc[2 * p + fi][g] = __builtin_amdgcn_mfma_f32_16x16x32_bf16(
                afr[fi][ks], bfr[g][ks], acc[2 * p + fi][g], 0, 0, 0);
      __builtin_amdgcn_s_setprio(0);
      __builtin_amdgcn_s_barrier();
    }
  }

  // epilogue
#pragma unroll
  for (int f = 0; f < 4; ++f){
    const int rowb = m0 + wr * 64 + f * 16 + ((l >> 4) << 2);
#pragma unroll
    for (int g = 0; g < 4; ++g){
      const int col = n0 + wc * 64 + g * 16 + (l & 15);
      const float bv = bias[col], gv = gate[col];
#pragma unroll
      for (int j = 0; j < 4; ++j){
        const int row = rowb + j;
        float v = acc[f][g][j] + bv;
        float gl = gelu_exact(v) * gv;
        if (MODE == 0){
          ((u16*)Cout)[(size_t)row * NDIM + col] = f2bf(gl);
        } else {
          size_t off = (size_t)row * NDIM + col;
          ((float*)Cout)[off] = xres[off] + gl;
        }
      }
    }
  }
}

// ---------------- launcher ----------------
extern "C" void kernel_launch(void* const* d_in, const int* in_sizes, int n_in,
                              void* d_out, int out_size, void* d_ws, size_t ws_size,
                              hipStream_t stream)
{
  const float* x       = (const float*)d_in[0];
  const int*   t       = (const int*)  d_in[1];
  const float* s       = (const float*)d_in[2];
  const float* fc1_w   = (const float*)d_in[3];
  const float* fc1_b   = (const float*)d_in[4];
  const float* fc2_w   = (const float*)d_in[5];
  const float* fc2_b   = (const float*)d_in[6];
  const float* efc1    = (const float*)d_in[7];
  const float* efc2    = (const float*)d_in[8];
  const float* sem_w   = (const float*)d_in[9];
  const float* sem_b   = (const float*)d_in[10];
  const float* rw      = (const float*)d_in[11];
  const float* larger_w= (const float*)d_in[12];
  const float* larger_b= (const float*)d_in[13];
  const float* elarger = (const float*)d_in[14];

  char* ws = (char*)d_ws;
  float* gfc1p   = (float*)(ws + 0);         //    8192 B  [2048]
  float* b1p     = (float*)(ws + 8192);      //    8192 B  [2048]
  float* gfc2    = (float*)(ws + 16384);     //    3072 B  [768]
  float* glarger = (float*)(ws + 19456);     //    3072 B  [768]
  u16*   Bw1     = (u16*)  (ws + 22528);     // 3145728 B  [2048][768] bf16
  u16*   Bw2     = (u16*)  (ws + 3168256);   // 3145728 B  [768][2048] bf16
  u16*   hpre    = (u16*)  (ws + 6313984);   // 25165824 B [16384][768] bf16
  u16*   Hm      = (u16*)  (ws + 31479808);  // 67108864 B [16384][2048] bf16
  // total 98,588,672 B

  prep_gates<<<8, 256, 0, stream>>>(s, t, efc1, efc2, elarger, fc1_b, gfc1p, b1p, gfc2, glarger);
  conv_w1<<<1536, 256, 0, stream>>>(fc1_w, Bw1);
  conv_w2<<<1536, 256, 0, stream>>>(fc2_w, Bw2);
  sem_route<<<512, 256, 0, stream>>>(x, t, sem_w, sem_b, rw, larger_w, larger_b, glarger, hpre);
  gemm128<0, 2048, 768><<<2048, 256, 0, stream>>>(hpre, Bw1, b1p, gfc1p, nullptr, (void*)Hm, 16);
  gemm128<1, 768, 2048><<<768, 256, 0, stream>>>(Hm, Bw2, fc2_b, gfc2, x, d_out, 6);
}

// Round 9
// 185.123 us; speedup vs baseline: 1.5967x; 1.0035x over previous
//
#include <hip/hip_runtime.h>
#include <stdint.h>
#include <math.h>

typedef unsigned short u16;
typedef __bf16 bf16x8 __attribute__((ext_vector_type(8)));
typedef u16 u16x8 __attribute__((ext_vector_type(8)));
typedef u16 u16x4 __attribute__((ext_vector_type(4)));
typedef float f32x4 __attribute__((ext_vector_type(4)));

#define NEG_ -10000.0f

__device__ __forceinline__ u16 f2bf(float f){
  unsigned u = __float_as_uint(f);
  unsigned r = (u + 0x7fffu + ((u >> 16) & 1u)) >> 16;
  return (u16)r;
}
__device__ __forceinline__ float bf2f(u16 v){
  return __uint_as_float(((unsigned)v) << 16);
}

// gelu exact via Abramowitz-Stegun 7.1.26 erf (|err| < 1.5e-7), ~14 VALU ops
__device__ __forceinline__ float gelu_exact(float v){
  float xe = v * 0.70710678118654752f;
  float ax = fabsf(xe);
  float k  = 1.0f / (1.0f + 0.3275911f * ax);
  float p  = ((((1.061405429f * k - 1.453152027f) * k + 1.421413741f) * k
               - 0.284496736f) * k + 0.254829592f) * k;
  float er = 1.0f - p * __expf(-ax * ax);
  er = copysignf(er, xe);
  return 0.5f * v * (1.0f + er);
}
__device__ __forceinline__ float sigmoidf_(float z){ return 1.f / (1.f + expf(-z)); }

__device__ __forceinline__ void async_load16(const void* g, void* lds){
  typedef const __attribute__((address_space(1))) unsigned int* gp_t;
  typedef __attribute__((address_space(3))) unsigned int* lp_t;
  __builtin_amdgcn_global_load_lds((gp_t)(uintptr_t)g, (lp_t)(uintptr_t)lds, 16, 0, 0);
}

__device__ __forceinline__ unsigned swz(unsigned o){ return o ^ ((o >> 3) & 0x70u); }

// ---------------- gates + padded bias ----------------
__global__ __launch_bounds__(256) void prep_gates(
    const float* __restrict__ s, const int* __restrict__ t,
    const float* __restrict__ efc1, const float* __restrict__ efc2,
    const float* __restrict__ elarger, const float* __restrict__ fc1_b,
    float* __restrict__ gfc1p, float* __restrict__ b1p,
    float* __restrict__ gfc2, float* __restrict__ glarger)
{
  int i = blockIdx.x * 256 + threadIdx.x;
  float sv = s[0]; int tt = t[0];
  if (i < 2048){
    float g = 0.f, b = 0.f;
    if (i < 2000){ g = sigmoidf_(sv * efc1[tt * 2000 + i]); b = fc1_b[i]; }
    gfc1p[i] = g; b1p[i] = b;
  }
  if (i < 768){
    gfc2[i]    = sigmoidf_(sv * efc2[tt * 768 + i]);
    glarger[i] = sigmoidf_(sv * elarger[tt * 768 + i]);
  }
}

// ---------------- weight conversions (zero-padded, vectorized) ----------------
__global__ __launch_bounds__(256) void conv_w1(const float* __restrict__ fc1_w, u16* __restrict__ Bw1){
  int q = blockIdx.x * 256 + threadIdx.x;              // 4 elems each, [2048][768]
  if (q >= 2048 * 192) return;
  int idx = q * 4;
  int n = idx / 768, k = idx % 768;
  ushort4 o;
  if (n < 2000){
    float4 v = *(const float4*)(fc1_w + (size_t)n * 768 + k);
    o.x = f2bf(v.x); o.y = f2bf(v.y); o.z = f2bf(v.z); o.w = f2bf(v.w);
  } else { o.x = o.y = o.z = o.w = 0; }
  *(ushort4*)(Bw1 + idx) = o;
}
__global__ __launch_bounds__(256) void conv_w2(const float* __restrict__ fc2_w, u16* __restrict__ Bw2){
  int q = blockIdx.x * 256 + threadIdx.x;              // 4 elems each, [768][2048]
  if (q >= 768 * 512) return;
  int idx = q * 4;
  int h = idx / 2048, k = idx % 2048;
  ushort4 o;
  if (k < 2000){                                        // 2000%4==0 -> whole float4 valid
    float4 v = *(const float4*)(fc2_w + (size_t)h * 2000 + k);
    o.x = f2bf(v.x); o.y = f2bf(v.y); o.z = f2bf(v.z); o.w = f2bf(v.w);
  } else { o.x = o.y = o.z = o.w = 0; }
  *(ushort4*)(Bw2 + idx) = o;
}

// ---------------- sem capsules (MFMA) + squash + routing + hpre, fully fused ----------
// 512 blocks x 256 threads; 32 tokens/block. (unchanged from R8 — passing, ~15-20 us)
__global__ __launch_bounds__(256) void sem_route(
    const float* __restrict__ x, const int* __restrict__ t_ptr,
    const float* __restrict__ sem_w, const float* __restrict__ sem_b,
    const float* __restrict__ rw, const float* __restrict__ larger_w,
    const float* __restrict__ larger_b, const float* __restrict__ glarger,
    u16* __restrict__ hpre)
{
  __shared__ __align__(16) u16 xbf[12 * 32 * 64];   // 49152 B, 12 subtiles of [32][64]
  __shared__ __align__(16) u16 wlds[2 * 32 * 64];   //  8192 B, double-buffered [32][64]
  __shared__ float semv_s[32][32];                  //  4096 B
  __shared__ float votes_s[32][9];                  //  1152 B

  const int tid  = (int)threadIdx.x;
  const int w    = tid >> 6, l = tid & 63;
  const int tok0 = (int)blockIdx.x * 32;

  // ---- stage x: 12 subtiles, reg-staged f32->bf16, T2-swizzled writes ----
  {
    const int r = tid >> 3;            // 0..31 token row
    const int kq = (tid & 7) * 8;      // 8 k-elems
    const float* xrow = x + (size_t)(tok0 + r) * 768 + kq;
#pragma unroll
    for (int j = 0; j < 12; ++j){
      float4 v0 = *(const float4*)(xrow + j * 64);
      float4 v1 = *(const float4*)(xrow + j * 64 + 4);
      u16x8 pk;
      pk[0] = f2bf(v0.x); pk[1] = f2bf(v0.y); pk[2] = f2bf(v0.z); pk[3] = f2bf(v0.w);
      pk[4] = f2bf(v1.x); pk[5] = f2bf(v1.y); pk[6] = f2bf(v1.z); pk[7] = f2bf(v1.w);
      unsigned o = (unsigned)(((j * 32 + r) << 7) + kq * 2);
      *(u16x8*)((char*)xbf + swz(o)) = pk;
    }
    // stage w subtile 0 into buf 0 (rows 30,31 zero)
    u16x8 pw = (u16x8)(u16)0;
    if (r < 30){
      const float* wr_ = sem_w + (size_t)r * 768 + kq;
      float4 v0 = *(const float4*)(wr_);
      float4 v1 = *(const float4*)(wr_ + 4);
      pw[0] = f2bf(v0.x); pw[1] = f2bf(v0.y); pw[2] = f2bf(v0.z); pw[3] = f2bf(v0.w);
      pw[4] = f2bf(v1.x); pw[5] = f2bf(v1.y); pw[6] = f2bf(v1.z); pw[7] = f2bf(v1.w);
    }
    unsigned ow = (unsigned)((r << 7) + kq * 2);
    *(u16x8*)((char*)wlds + swz(ow)) = pw;
  }
  __syncthreads();

  // ---- MFMA projection: wave w -> token rows (w>>1)*16, caps (w&1)*16 ----
  const int rowblk = (w >> 1) * 16, nb = (w & 1) * 16;
  f32x4 acc = (f32x4){0.f, 0.f, 0.f, 0.f};
  for (int j = 0; j < 12; ++j){
    const int buf = j & 1;
    bf16x8 af[2], bf[2];
#pragma unroll
    for (int ks = 0; ks < 2; ++ks){
      unsigned oa = (unsigned)(((j * 32 + rowblk + (l & 15)) << 7) + ks * 64 + ((l >> 4) << 4));
      af[ks] = *(const bf16x8*)((const char*)xbf + swz(oa));
      unsigned ob = (unsigned)(((buf * 32 + nb + (l & 15)) << 7) + ks * 64 + ((l >> 4) << 4));
      bf[ks] = *(const bf16x8*)((const char*)wlds + swz(ob));
    }
    // stage w subtile j+1 into the other buffer
    if (j + 1 < 12){
      const int r = tid >> 3, kq = (tid & 7) * 8;
      u16x8 pw = (u16x8)(u16)0;
      if (r < 30){
        const float* wr_ = sem_w + (size_t)r * 768 + (j + 1) * 64 + kq;
        float4 v0 = *(const float4*)(wr_);
        float4 v1 = *(const float4*)(wr_ + 4);
        pw[0] = f2bf(v0.x); pw[1] = f2bf(v0.y); pw[2] = f2bf(v0.z); pw[3] = f2bf(v0.w);
        pw[4] = f2bf(v1.x); pw[5] = f2bf(v1.y); pw[6] = f2bf(v1.z); pw[7] = f2bf(v1.w);
      }
      unsigned ow = (unsigned)(((((j + 1) & 1) * 32 + r) << 7) + kq * 2);
      *(u16x8*)((char*)wlds + swz(ow)) = pw;
    }
#pragma unroll
    for (int ks = 0; ks < 2; ++ks)
      acc = __builtin_amdgcn_mfma_f32_16x16x32_bf16(af[ks], bf[ks], acc, 0, 0, 0);
    __syncthreads();
  }
  // C layout: col = lane&15 (cap), row = (lane>>4)*4 + j (token within 16-block)
#pragma unroll
  for (int jj = 0; jj < 4; ++jj)
    semv_s[rowblk + (l >> 4) * 4 + jj][nb + (l & 15)] = acc[jj];
  __syncthreads();

  // ---- squash + dynamic routing per (token, m); 96 active threads ----
  if (tid < 96){
    const int tk = tid & 31, m = tid >> 5;
    const int tt = t_ptr[0];
    float s30[30];
#pragma unroll
    for (int jf = 0; jf < 30; ++jf){
      const int c = jf / 10, tcap = jf % 10;
      const int wrow = tcap * 3 + c;
      s30[jf] = semv_s[tk][wrow] + sem_b[wrow];
    }
#pragma unroll
    for (int c = 0; c < 3; ++c){
      float sq = 0.f;
#pragma unroll
      for (int jf = 0; jf < 10; ++jf){ float v = s30[c * 10 + jf]; sq += v * v; }
      sq += 1e-16f;
      const float scale = (sq / (1.f + sq)) / sqrtf(sq);
#pragma unroll
      for (int jf = 0; jf < 10; ++jf) s30[c * 10 + jf] *= scale;
    }
    float p[10][3];
#pragma unroll
    for (int r = 0; r < 10; r++){
      const float x0 = s30[r * 3 + 0], x1 = s30[r * 3 + 1], x2 = s30[r * 3 + 2];
      const float* rwp = rw + m * 90 + r * 9;
#pragma unroll
      for (int d = 0; d < 3; d++)
        p[r][d] = x0 * rwp[d] + x1 * rwp[3 + d] + x2 * rwp[6 + d];
    }
    float lg[10];
#pragma unroll
    for (int r = 0; r < 10; r++) lg[r] = 0.f;
    float v0 = 0.f, v1 = 0.f, v2 = 0.f;
    for (int it = 0; it < 3; ++it){
      float lr[10]; float mx = -3.0e38f;
#pragma unroll
      for (int r = 0; r < 10; r++){ lr[r] = (r <= tt) ? lg[r] : NEG_; mx = fmaxf(mx, lr[r]); }
      float e[10]; float sum = 0.f;
#pragma unroll
      for (int r = 0; r < 10; r++){ e[r] = expf(lr[r] - mx); sum += e[r]; }
      const float inv = 1.f / sum;
      v0 = 0.f; v1 = 0.f; v2 = 0.f;
#pragma unroll
      for (int r = 0; r < 10; r++){
        const float pr = e[r] * inv;
        v0 += pr * p[r][0]; v1 += pr * p[r][1]; v2 += pr * p[r][2];
      }
      if (it < 2){
        float sq = v0 * v0 + v1 * v1 + v2 * v2 + 1e-16f;
        float scale = (sq / (1.f + sq)) / sqrtf(sq);
        const float o0 = v0 * scale, o1 = v1 * scale, o2 = v2 * scale;
#pragma unroll
        for (int r = 0; r < 10; r++) lg[r] += p[r][0] * o0 + p[r][1] * o1 + p[r][2] * o2;
      }
    }
    votes_s[tk][m * 3 + 0] = v0;
    votes_s[tk][m * 3 + 1] = v1;
    votes_s[tk][m * 3 + 2] = v2;
  }
  __syncthreads();

  // ---- hpre: 192 threads, thread = h-quad q; x read back from LDS (bf16) ----
  if (tid < 192){
    const int q = tid, h0 = q * 4;
    float lw36[36];
    const float4* lwq = (const float4*)(larger_w + (size_t)h0 * 9);
#pragma unroll
    for (int k = 0; k < 9; k++){
      float4 tq = lwq[k];
      lw36[4*k] = tq.x; lw36[4*k+1] = tq.y; lw36[4*k+2] = tq.z; lw36[4*k+3] = tq.w;
    }
    const float4 bq = *(const float4*)(larger_b + h0);
    const float4 gq = *(const float4*)(glarger + h0);
    const float bb[4] = {bq.x, bq.y, bq.z, bq.w};
    const float gg[4] = {gq.x, gq.y, gq.z, gq.w};
    const int kstep = h0 >> 6, col = h0 & 63;
    for (int tk = 0; tk < 32; ++tk){
      float vt[9];
#pragma unroll
      for (int k = 0; k < 9; k++) vt[k] = votes_s[tk][k];
      unsigned o = (unsigned)(((kstep * 32 + tk) << 7) + col * 2);
      u16x4 xb = *(const u16x4*)((const char*)xbf + swz(o));
      u16 oa[4];
#pragma unroll
      for (int r = 0; r < 4; ++r){
        float a = bb[r];
#pragma unroll
        for (int k = 0; k < 9; ++k) a += vt[k] * lw36[r * 9 + k];
        oa[r] = f2bf(bf2f(xb[r]) + a * gg[r]);
      }
      ushort4 ov; ov.x = oa[0]; ov.y = oa[1]; ov.z = oa[2]; ov.w = oa[3];
      *(ushort4*)(hpre + (size_t)(tok0 + tk) * 768 + h0) = ov;
    }
  }
}

// ---------------- 128x128 bf16 MFMA GEMM, C = A(MxK) * B(NxK)^T, 2 blocks/CU ------------
// 64KB LDS double-buffer, 2 co-resident blocks. Per K-tile j, 2 phases of 16 MFMA.
// Counted-vmcnt ledger (never 0 in main loop):
//   ph0: read all B-frags + A-frags(fm0,1); stage A(j+1) -> As[(j+1)&1]
//   ph1: read A-frags(fm2,3); stage B(j+2) -> Bs[j&1]; vmcnt(4)
// NO sched_barrier, NO explicit lgkmcnt in the loop (m141 lesson): compiler emits
// counted lgkmcnt per-MFMA, so late ds_reads overlap early MFMAs. Race-safety:
// staging B(j+2) issues only after the post-MFMA barrier of ph0, and every wave's
// bfr reads complete before its ph0 MFMAs (data dep) -> no write-before-read.
// MODE 0: store bf16(gelu(acc+bias)*gate);  MODE 1: store f32 xres + gelu(acc+bias)*gate.
template<int MODE, int NDIM, int KDIM>
__global__ __launch_bounds__(256, 2) void gemm128(
    const u16* __restrict__ A, const u16* __restrict__ B,
    const float* __restrict__ bias, const float* __restrict__ gate,
    const float* __restrict__ xres, void* __restrict__ Cout, int NT_N)
{
  __shared__ __align__(16) u16 As[2][8192];   // [buf][128 rows x 64 k]
  __shared__ __align__(16) u16 Bs[2][8192];
  constexpr int NT = KDIM / 64;

  const int nwg = (int)gridDim.x;              // multiple of 8
  const int cpx = nwg >> 3;
  const int wg  = ((int)blockIdx.x & 7) * cpx + ((int)blockIdx.x >> 3);
  const int bm = wg / NT_N, bn = wg % NT_N;
  const int m0 = bm * 128, n0 = bn * 128;
  const int tid = (int)threadIdx.x;
  const int w = tid >> 6, l = tid & 63;
  const int wr = w >> 1, wc = w & 1;           // 2 x 2 wave grid; wave tile 64 x 64

  f32x4 acc[4][4];
#pragma unroll
  for (int i = 0; i < 4; i++)
#pragma unroll
    for (int j = 0; j < 4; j++)
      acc[i][j] = (f32x4){0.f, 0.f, 0.f, 0.f};

  // stage one 128x64 tile (16KB): linear LDS dest, swizzled global source
  auto stage_tile = [&](const u16* __restrict__ src, int r0, int k0, u16* lds){
#pragma unroll
    for (int jj = 0; jj < 4; ++jj){
      unsigned o  = (unsigned)(jj * 4096 + tid * 16);
      unsigned lo = swz(o);
      const u16* g = src + (size_t)(r0 + (int)(lo >> 7)) * KDIM + (k0 + (int)((lo & 127u) >> 1));
      async_load16(g, (char*)lds + jj * 4096 + w * 1024);
    }
  };

  // prologue: A(0), B(0), B(1); keep B(1) (4 loads) in flight
  stage_tile(A, m0, 0,  As[0]);
  stage_tile(B, n0, 0,  Bs[0]);
  stage_tile(B, n0, 64, Bs[1]);
  asm volatile("s_waitcnt vmcnt(4)");
  __builtin_amdgcn_s_barrier();

#pragma unroll 2
  for (int j = 0; j < NT; ++j){
    const int buf = j & 1;
    const char* abase = (const char*)As[buf];
    const char* bbase = (const char*)Bs[buf];
    bf16x8 bfr[4][2];
#pragma unroll
    for (int p = 0; p < 2; ++p){
      if (p == 0){
#pragma unroll
        for (int g = 0; g < 4; ++g)
#pragma unroll
          for (int ks = 0; ks < 2; ++ks){
            unsigned o = (unsigned)(((wc * 64 + g * 16 + (l & 15)) << 7) + ks * 64 + ((l >> 4) << 4));
            bfr[g][ks] = *(const bf16x8*)(bbase + swz(o));
          }
      }
      bf16x8 afr[2][2];
#pragma unroll
      for (int fi = 0; fi < 2; ++fi)
#pragma unroll
        for (int ks = 0; ks < 2; ++ks){
          unsigned o = (unsigned)(((wr * 64 + (2 * p + fi) * 16 + (l & 15)) << 7) + ks * 64 + ((l >> 4) << 4));
          afr[fi][ks] = *(const bf16x8*)(abase + swz(o));
        }
      if (p == 0 && j + 1 < NT) stage_tile(A, m0, (j + 1) * 64, As[(j + 1) & 1]);
      if (p == 1 && j + 2 < NT) stage_tile(B, n0, (j + 2) * 64, Bs[buf]);
      if (p == 1){
        if (j < NT - 2)       asm volatile("s_waitcnt vmcnt(4)");
        else if (j == NT - 2) asm volatile("s_waitcnt vmcnt(0)");
      }
      __builtin_amdgcn_s_barrier();
      __builtin_amdgcn_s_setprio(1);
#pragma unroll
      for (int ks = 0; ks < 2; ++ks)
#pragma unroll
        for (int fi = 0; fi < 2; ++fi)
#pragma unroll
          for (int g = 0; g < 4; ++g)
            acc[2 * p + fi][g] = __builtin_amdgcn_mfma_f32_16x16x32_bf16(
                afr[fi][ks], bfr[g][ks], acc[2 * p + fi][g], 0, 0, 0);
      __builtin_amdgcn_s_setprio(0);
      __builtin_amdgcn_s_barrier();
    }
  }

  // epilogue
#pragma unroll
  for (int f = 0; f < 4; ++f){
    const int rowb = m0 + wr * 64 + f * 16 + ((l >> 4) << 2);
#pragma unroll
    for (int g = 0; g < 4; ++g){
      const int col = n0 + wc * 64 + g * 16 + (l & 15);
      const float bv = bias[col], gv = gate[col];
#pragma unroll
      for (int j = 0; j < 4; ++j){
        const int row = rowb + j;
        float v = acc[f][g][j] + bv;
        float gl = gelu_exact(v) * gv;
        if (MODE == 0){
          ((u16*)Cout)[(size_t)row * NDIM + col] = f2bf(gl);
        } else {
          size_t off = (size_t)row * NDIM + col;
          ((float*)Cout)[off] = xres[off] + gl;
        }
      }
    }
  }
}

// ---------------- launcher ----------------
extern "C" void kernel_launch(void* const* d_in, const int* in_sizes, int n_in,
                              void* d_out, int out_size, void* d_ws, size_t ws_size,
                              hipStream_t stream)
{
  const float* x       = (const float*)d_in[0];
  const int*   t       = (const int*)  d_in[1];
  const float* s       = (const float*)d_in[2];
  const float* fc1_w   = (const float*)d_in[3];
  const float* fc1_b   = (const float*)d_in[4];
  const float* fc2_w   = (const float*)d_in[5];
  const float* fc2_b   = (const float*)d_in[6];
  const float* efc1    = (const float*)d_in[7];
  const float* efc2    = (const float*)d_in[8];
  const float* sem_w   = (const float*)d_in[9];
  const float* sem_b   = (const float*)d_in[10];
  const float* rw      = (const float*)d_in[11];
  const float* larger_w= (const float*)d_in[12];
  const float* larger_b= (const float*)d_in[13];
  const float* elarger = (const float*)d_in[14];

  char* ws = (char*)d_ws;
  float* gfc1p   = (float*)(ws + 0);         //    8192 B  [2048]
  float* b1p     = (float*)(ws + 8192);      //    8192 B  [2048]
  float* gfc2    = (float*)(ws + 16384);     //    3072 B  [768]
  float* glarger = (float*)(ws + 19456);     //    3072 B  [768]
  u16*   Bw1     = (u16*)  (ws + 22528);     // 3145728 B  [2048][768] bf16
  u16*   Bw2     = (u16*)  (ws + 3168256);   // 3145728 B  [768][2048] bf16
  u16*   hpre    = (u16*)  (ws + 6313984);   // 25165824 B [16384][768] bf16
  u16*   Hm      = (u16*)  (ws + 31479808);  // 67108864 B [16384][2048] bf16
  // total 98,588,672 B

  prep_gates<<<8, 256, 0, stream>>>(s, t, efc1, efc2, elarger, fc1_b, gfc1p, b1p, gfc2, glarger);
  conv_w1<<<1536, 256, 0, stream>>>(fc1_w, Bw1);
  conv_w2<<<1536, 256, 0, stream>>>(fc2_w, Bw2);
  sem_route<<<512, 256, 0, stream>>>(x, t, sem_w, sem_b, rw, larger_w, larger_b, glarger, hpre);
  gemm128<0, 2048, 768><<<2048, 256, 0, stream>>>(hpre, Bw1, b1p, gfc1p, nullptr, (void*)Hm, 16);
  gemm128<1, 768, 2048><<<768, 256, 0, stream>>>(Hm, Bw2, fc2_b, gfc2, x, d_out, 6);
}